// Round 1
// baseline (207.217 us; speedup 1.0000x reference)
//
#include <hip/hip_runtime.h>
#include <hip/hip_bf16.h>

#define EMB_DIM 512
#define B_SZ 1024
#define LT 50
#define LD 200
#define H_D 1024
#define K_FC 2048   // 4*EMB_DIM
#define NCLS 10
#define BN_EPS 1e-5f
#define NEGV -1e30f

// ---------------- Kernel 1: SWEM pooling (gather + masked avg/max) --------
// One block per batch row; 256 threads, each owns 2 dims (float2).
__global__ __launch_bounds__(256) void swem_pool_kernel(
    const int* __restrict__ title, const int* __restrict__ desc,
    const int* __restrict__ t_len, const int* __restrict__ d_len,
    const float* __restrict__ emb, float* __restrict__ swem) {
  const int b = blockIdx.x;
  const int d = threadIdx.x * 2;

  const int tl = t_len[b];
  const int dl = d_len[b];

  float2 ts = make_float2(0.f, 0.f);
  float2 tm = make_float2(NEGV, NEGV);
  for (int j = 0; j < tl; ++j) {
    int tok = title[b * LT + j];
    float2 e = *reinterpret_cast<const float2*>(&emb[(size_t)tok * EMB_DIM + d]);
    ts.x += e.x; ts.y += e.y;
    tm.x = fmaxf(tm.x, e.x); tm.y = fmaxf(tm.y, e.y);
  }
  float2 dsm = make_float2(0.f, 0.f);
  float2 dmx = make_float2(NEGV, NEGV);
  for (int j = 0; j < dl; ++j) {
    int tok = desc[b * LD + j];
    float2 e = *reinterpret_cast<const float2*>(&emb[(size_t)tok * EMB_DIM + d]);
    dsm.x += e.x; dsm.y += e.y;
    dmx.x = fmaxf(dmx.x, e.x); dmx.y = fmaxf(dmx.y, e.y);
  }

  const float it = 1.0f / (float)tl;
  const float id = 1.0f / (float)dl;
  float* row = swem + (size_t)b * K_FC;
  *reinterpret_cast<float2*>(&row[0 * EMB_DIM + d]) = make_float2(ts.x * it, ts.y * it);
  *reinterpret_cast<float2*>(&row[1 * EMB_DIM + d]) = tm;
  *reinterpret_cast<float2*>(&row[2 * EMB_DIM + d]) = make_float2(dsm.x * id, dsm.y * id);
  *reinterpret_cast<float2*>(&row[3 * EMB_DIM + d]) = dmx;
}

// ---------------- Kernel 2: FC GEMM  h = swem @ W_fc + b_fc ---------------
// A: [1024, 2048] row-major, B: [2048, 1024] row-major, C: [1024, 1024].
// 64x64 block tile, BK=16, 256 threads, 4x4 micro-tile per thread.
#define BM 64
#define BN 64
#define BK 16
__global__ __launch_bounds__(256) void gemm_fc_kernel(
    const float* __restrict__ A, const float* __restrict__ Bm,
    const float* __restrict__ bias, float* __restrict__ C) {
  __shared__ float As[BK][BM];
  __shared__ float Bs[BK][BN];

  const int tid = threadIdx.x;
  const int tx = tid & 15;   // col group 0..15
  const int ty = tid >> 4;   // row group 0..15
  const int row0 = blockIdx.y * BM;
  const int col0 = blockIdx.x * BN;

  const int ar = tid >> 2;          // 0..63 (A tile row)
  const int ak = (tid & 3) << 2;    // 0,4,8,12 (A tile k)
  const int bk = tid >> 4;          // 0..15 (B tile k)
  const int bc = (tid & 15) << 2;   // 0..60 (B tile col)

  float acc[4][4] = {};

  for (int k0 = 0; k0 < K_FC; k0 += BK) {
    float4 av = *reinterpret_cast<const float4*>(&A[(size_t)(row0 + ar) * K_FC + k0 + ak]);
    float4 bv = *reinterpret_cast<const float4*>(&Bm[(size_t)(k0 + bk) * H_D + col0 + bc]);
    __syncthreads();
    As[ak + 0][ar] = av.x;
    As[ak + 1][ar] = av.y;
    As[ak + 2][ar] = av.z;
    As[ak + 3][ar] = av.w;
    *reinterpret_cast<float4*>(&Bs[bk][bc]) = bv;
    __syncthreads();

#pragma unroll
    for (int kk = 0; kk < BK; ++kk) {
      float4 a4 = *reinterpret_cast<const float4*>(&As[kk][ty * 4]);
      float4 b4 = *reinterpret_cast<const float4*>(&Bs[kk][tx * 4]);
      float a[4] = {a4.x, a4.y, a4.z, a4.w};
      float b[4] = {b4.x, b4.y, b4.z, b4.w};
#pragma unroll
      for (int i = 0; i < 4; ++i)
#pragma unroll
        for (int j = 0; j < 4; ++j)
          acc[i][j] += a[i] * b[j];
    }
  }

#pragma unroll
  for (int i = 0; i < 4; ++i) {
    int r = row0 + ty * 4 + i;
    int c = col0 + tx * 4;
    float4 o;
    o.x = acc[i][0] + bias[c + 0];
    o.y = acc[i][1] + bias[c + 1];
    o.z = acc[i][2] + bias[c + 2];
    o.w = acc[i][3] + bias[c + 3];
    *reinterpret_cast<float4*>(&C[(size_t)r * H_D + c]) = o;
  }
}

// ------------- Kernel 3a: BN partial sums (per-column, over row chunks) ---
// grid (4 col-chunks, 16 row-chunks), 256 threads. Each thread: one column,
// 64 rows.
__global__ __launch_bounds__(256) void bn_part_kernel(
    const float* __restrict__ h, float* __restrict__ psum, float* __restrict__ psq) {
  const int col = blockIdx.x * 256 + threadIdx.x;
  const int r0 = blockIdx.y * 64;
  float s = 0.f, q = 0.f;
  for (int r = r0; r < r0 + 64; ++r) {
    float v = h[(size_t)r * H_D + col];
    s += v;
    q += v * v;
  }
  psum[blockIdx.y * H_D + col] = s;
  psq[blockIdx.y * H_D + col] = q;
}

// ------------- Kernel 3b: finalize BN -> scale/shift ----------------------
__global__ __launch_bounds__(256) void bn_final_kernel(
    const float* __restrict__ psum, const float* __restrict__ psq,
    const float* __restrict__ gamma, const float* __restrict__ beta,
    float* __restrict__ scale, float* __restrict__ shift) {
  const int col = blockIdx.x * 256 + threadIdx.x;
  float s = 0.f, q = 0.f;
#pragma unroll
  for (int i = 0; i < 16; ++i) {
    s += psum[i * H_D + col];
    q += psq[i * H_D + col];
  }
  const float inv_n = 1.0f / (float)B_SZ;
  float mean = s * inv_n;
  float var = q * inv_n - mean * mean;
  float rstd = rsqrtf(var + BN_EPS);
  float sc = rstd * gamma[col];
  scale[col] = sc;
  shift[col] = beta[col] - mean * sc;
}

// ------------- Kernel 4: BN apply + ReLU + classifier GEMM ----------------
// One block per batch row. out[row, 0..9] = relu(h*scale+shift) @ W_clf + b.
__global__ __launch_bounds__(256) void clf_kernel(
    const float* __restrict__ h, const float* __restrict__ scale,
    const float* __restrict__ shift, const float* __restrict__ W,
    const float* __restrict__ bclf, float* __restrict__ out) {
  const int row = blockIdx.x;
  const int tid = threadIdx.x;
  float acc[NCLS] = {};
  for (int k = tid; k < H_D; k += 256) {
    float v = h[(size_t)row * H_D + k] * scale[k] + shift[k];
    v = fmaxf(v, 0.f);
    const float* w = &W[(size_t)k * NCLS];
#pragma unroll
    for (int j = 0; j < NCLS; ++j) acc[j] += v * w[j];
  }
#pragma unroll
  for (int j = 0; j < NCLS; ++j) {
    float v = acc[j];
#pragma unroll
    for (int off = 32; off > 0; off >>= 1) v += __shfl_down(v, off, 64);
    acc[j] = v;
  }
  __shared__ float part[4][NCLS];
  const int wave = tid >> 6;
  const int lane = tid & 63;
  if (lane == 0) {
#pragma unroll
    for (int j = 0; j < NCLS; ++j) part[wave][j] = acc[j];
  }
  __syncthreads();
  if (tid < NCLS) {
    float s = part[0][tid] + part[1][tid] + part[2][tid] + part[3][tid] + bclf[tid];
    out[(size_t)row * NCLS + tid] = s;
  }
}

extern "C" void kernel_launch(void* const* d_in, const int* in_sizes, int n_in,
                              void* d_out, int out_size, void* d_ws, size_t ws_size,
                              hipStream_t stream) {
  const int* title = (const int*)d_in[0];
  const int* desc  = (const int*)d_in[1];
  const int* t_len = (const int*)d_in[2];
  const int* d_len = (const int*)d_in[3];
  const float* emb   = (const float*)d_in[4];
  const float* W_fc  = (const float*)d_in[5];
  const float* b_fc  = (const float*)d_in[6];
  const float* gamma = (const float*)d_in[7];
  const float* beta  = (const float*)d_in[8];
  const float* W_clf = (const float*)d_in[9];
  const float* b_clf = (const float*)d_in[10];
  float* out = (float*)d_out;

  float* swem  = (float*)d_ws;                 // 1024*2048
  float* h     = swem + (size_t)B_SZ * K_FC;   // 1024*1024
  float* psum  = h + (size_t)B_SZ * H_D;       // 16*1024
  float* psq   = psum + 16 * H_D;              // 16*1024
  float* scale = psq + 16 * H_D;               // 1024
  float* shift = scale + H_D;                  // 1024

  swem_pool_kernel<<<B_SZ, 256, 0, stream>>>(title, desc, t_len, d_len, emb, swem);
  gemm_fc_kernel<<<dim3(H_D / BN, B_SZ / BM), 256, 0, stream>>>(swem, W_fc, b_fc, h);
  bn_part_kernel<<<dim3(H_D / 256, 16), 256, 0, stream>>>(h, psum, psq);
  bn_final_kernel<<<H_D / 256, 256, 0, stream>>>(psum, psq, gamma, beta, scale, shift);
  clf_kernel<<<B_SZ, 256, 0, stream>>>(h, scale, shift, W_clf, b_clf, out);
}

// Round 2
// 124.473 us; speedup vs baseline: 1.6648x; 1.6648x over previous
//
#include <hip/hip_runtime.h>
#include <hip/hip_bf16.h>

#define EMB_DIM 512
#define B_SZ 1024
#define LT 50
#define LD 200
#define H_D 1024
#define K_FC 2048   // 4*EMB_DIM
#define NCLS 10
#define BN_EPS 1e-5f
#define NEGV -1e30f

typedef short short8 __attribute__((ext_vector_type(8)));
typedef float f32x4 __attribute__((ext_vector_type(4)));

// XOR swizzle: spread 128B-stride rows across banks (guide §6 G4)
#define SWZ(r, b) ((b) ^ (((r) & 7) << 4))

// ---------------- Kernel 1: SWEM pooling (gather + masked avg/max) --------
// One block per batch row; 256 threads, each owns 2 dims. Emits bf16.
__global__ __launch_bounds__(256) void swem_pool_kernel(
    const int* __restrict__ title, const int* __restrict__ desc,
    const int* __restrict__ t_len, const int* __restrict__ d_len,
    const float* __restrict__ emb, __hip_bfloat16* __restrict__ swem) {
  const int b = blockIdx.x;
  const int d = threadIdx.x * 2;

  const int tl = t_len[b];
  const int dl = d_len[b];

  float2 ts = make_float2(0.f, 0.f);
  float2 tm = make_float2(NEGV, NEGV);
  for (int j = 0; j < tl; ++j) {
    int tok = title[b * LT + j];
    float2 e = *reinterpret_cast<const float2*>(&emb[(size_t)tok * EMB_DIM + d]);
    ts.x += e.x; ts.y += e.y;
    tm.x = fmaxf(tm.x, e.x); tm.y = fmaxf(tm.y, e.y);
  }
  float2 dsm = make_float2(0.f, 0.f);
  float2 dmx = make_float2(NEGV, NEGV);
  for (int j = 0; j < dl; ++j) {
    int tok = desc[b * LD + j];
    float2 e = *reinterpret_cast<const float2*>(&emb[(size_t)tok * EMB_DIM + d]);
    dsm.x += e.x; dsm.y += e.y;
    dmx.x = fmaxf(dmx.x, e.x); dmx.y = fmaxf(dmx.y, e.y);
  }

  const float it = 1.0f / (float)tl;
  const float id = 1.0f / (float)dl;
  __hip_bfloat16* row = swem + (size_t)b * K_FC;
  __hip_bfloat162 v;
  v.x = __float2bfloat16(ts.x * it); v.y = __float2bfloat16(ts.y * it);
  *reinterpret_cast<__hip_bfloat162*>(&row[0 * EMB_DIM + d]) = v;
  v.x = __float2bfloat16(tm.x); v.y = __float2bfloat16(tm.y);
  *reinterpret_cast<__hip_bfloat162*>(&row[1 * EMB_DIM + d]) = v;
  v.x = __float2bfloat16(dsm.x * id); v.y = __float2bfloat16(dsm.y * id);
  *reinterpret_cast<__hip_bfloat162*>(&row[2 * EMB_DIM + d]) = v;
  v.x = __float2bfloat16(dmx.x); v.y = __float2bfloat16(dmx.y);
  *reinterpret_cast<__hip_bfloat162*>(&row[3 * EMB_DIM + d]) = v;
}

// ------------- Kernel 2: transpose+convert W_fc [2048][1024]f32 -> Wt [1024][2048]bf16
__global__ __launch_bounds__(256) void transpose_wfc_kernel(
    const float* __restrict__ W, __hip_bfloat16* __restrict__ Wt) {
  __shared__ float t[64][65];
  const int tid = threadIdx.x;
  const int k0 = blockIdx.y * 64;
  const int n0 = blockIdx.x * 64;
#pragma unroll
  for (int i = 0; i < 16; ++i) {
    int idx = i * 256 + tid;
    int r = idx >> 6, c = idx & 63;
    t[r][c] = W[(size_t)(k0 + r) * H_D + n0 + c];
  }
  __syncthreads();
#pragma unroll
  for (int i = 0; i < 16; ++i) {
    int idx = i * 256 + tid;
    int r = idx >> 6, c = idx & 63;
    Wt[(size_t)(n0 + r) * K_FC + k0 + c] = __float2bfloat16(t[c][r]);
  }
}

// ---------------- Kernel 3: MFMA GEMM  h = swem @ W_fc + b_fc (NT, bf16 in, f32 out)
// 64x64 tile, BK=64, 4 waves, each wave 32x32 (2x2 frags of 16x16x32).
__global__ __launch_bounds__(256) void gemm_mfma_kernel(
    const __hip_bfloat16* __restrict__ A,   // [1024][2048] bf16 (swem)
    const __hip_bfloat16* __restrict__ Bt,  // [1024][2048] bf16 (W_fc^T)
    const float* __restrict__ bias, float* __restrict__ C) {
  __shared__ unsigned char As[8192];
  __shared__ unsigned char Bs[8192];
  const int tid = threadIdx.x;
  const int lane = tid & 63;
  const int wave = tid >> 6;
  const int wr = wave >> 1, wc = wave & 1;
  const int m0 = blockIdx.y * 64, n0 = blockIdx.x * 64;

  f32x4 acc[2][2] = {};

  // staging: 512 chunks of 16B per tile; each thread 2 chunks per operand
  const int c0 = tid * 2, c1 = tid * 2 + 1;
  const int r0s = c0 >> 3, o0 = c0 & 7;
  const int r1s = c1 >> 3, o1 = c1 & 7;
  const int hi = lane >> 4;
  const int lo = lane & 15;

  for (int k0 = 0; k0 < K_FC; k0 += 64) {
    float4 a0 = *reinterpret_cast<const float4*>(A + (size_t)(m0 + r0s) * K_FC + k0 + o0 * 8);
    float4 a1 = *reinterpret_cast<const float4*>(A + (size_t)(m0 + r1s) * K_FC + k0 + o1 * 8);
    float4 b0 = *reinterpret_cast<const float4*>(Bt + (size_t)(n0 + r0s) * K_FC + k0 + o0 * 8);
    float4 b1 = *reinterpret_cast<const float4*>(Bt + (size_t)(n0 + r1s) * K_FC + k0 + o1 * 8);
    __syncthreads();
    *reinterpret_cast<float4*>(As + SWZ(r0s, r0s * 128 + o0 * 16)) = a0;
    *reinterpret_cast<float4*>(As + SWZ(r1s, r1s * 128 + o1 * 16)) = a1;
    *reinterpret_cast<float4*>(Bs + SWZ(r0s, r0s * 128 + o0 * 16)) = b0;
    *reinterpret_cast<float4*>(Bs + SWZ(r1s, r1s * 128 + o1 * 16)) = b1;
    __syncthreads();

#pragma unroll
    for (int kks = 0; kks < 2; ++kks) {
      short8 af[2], bfr[2];
#pragma unroll
      for (int mi = 0; mi < 2; ++mi) {
        int r = wr * 32 + mi * 16 + lo;
        af[mi] = *reinterpret_cast<const short8*>(As + SWZ(r, r * 128 + kks * 64 + hi * 16));
      }
#pragma unroll
      for (int ni = 0; ni < 2; ++ni) {
        int r = wc * 32 + ni * 16 + lo;
        bfr[ni] = *reinterpret_cast<const short8*>(Bs + SWZ(r, r * 128 + kks * 64 + hi * 16));
      }
#pragma unroll
      for (int mi = 0; mi < 2; ++mi)
#pragma unroll
        for (int ni = 0; ni < 2; ++ni)
          acc[mi][ni] = __builtin_amdgcn_mfma_f32_16x16x32_bf16(af[mi], bfr[ni], acc[mi][ni], 0, 0, 0);
    }
  }

  // epilogue: C/D layout col=lane&15, row=(lane>>4)*4+reg (m89-verified)
#pragma unroll
  for (int mi = 0; mi < 2; ++mi) {
#pragma unroll
    for (int ni = 0; ni < 2; ++ni) {
      int col = n0 + wc * 32 + ni * 16 + lo;
      float bv = bias[col];
#pragma unroll
      for (int r = 0; r < 4; ++r) {
        int rowm = m0 + wr * 32 + mi * 16 + hi * 4 + r;
        C[(size_t)rowm * H_D + col] = acc[mi][ni][r] + bv;
      }
    }
  }
}

// ------------- Kernel 4a: BN partial sums -------------------------------
__global__ __launch_bounds__(256) void bn_part_kernel(
    const float* __restrict__ h, float* __restrict__ psum, float* __restrict__ psq) {
  const int col = blockIdx.x * 256 + threadIdx.x;
  const int r0 = blockIdx.y * 64;
  float s = 0.f, q = 0.f;
  for (int r = r0; r < r0 + 64; ++r) {
    float v = h[(size_t)r * H_D + col];
    s += v;
    q += v * v;
  }
  psum[blockIdx.y * H_D + col] = s;
  psq[blockIdx.y * H_D + col] = q;
}

// ------------- Kernel 4b: finalize BN -> scale/shift ----------------------
__global__ __launch_bounds__(256) void bn_final_kernel(
    const float* __restrict__ psum, const float* __restrict__ psq,
    const float* __restrict__ gamma, const float* __restrict__ beta,
    float* __restrict__ scale, float* __restrict__ shift) {
  const int col = blockIdx.x * 256 + threadIdx.x;
  float s = 0.f, q = 0.f;
#pragma unroll
  for (int i = 0; i < 16; ++i) {
    s += psum[i * H_D + col];
    q += psq[i * H_D + col];
  }
  const float inv_n = 1.0f / (float)B_SZ;
  float mean = s * inv_n;
  float var = q * inv_n - mean * mean;
  float rstd = rsqrtf(var + BN_EPS);
  float sc = rstd * gamma[col];
  scale[col] = sc;
  shift[col] = beta[col] - mean * sc;
}

// ------------- Kernel 5: BN apply + ReLU + classifier GEMM ----------------
__global__ __launch_bounds__(256) void clf_kernel(
    const float* __restrict__ h, const float* __restrict__ scale,
    const float* __restrict__ shift, const float* __restrict__ W,
    const float* __restrict__ bclf, float* __restrict__ out) {
  const int row = blockIdx.x;
  const int tid = threadIdx.x;
  float acc[NCLS] = {};
  for (int k = tid; k < H_D; k += 256) {
    float v = h[(size_t)row * H_D + k] * scale[k] + shift[k];
    v = fmaxf(v, 0.f);
    const float* w = &W[(size_t)k * NCLS];
#pragma unroll
    for (int j = 0; j < NCLS; ++j) acc[j] += v * w[j];
  }
#pragma unroll
  for (int j = 0; j < NCLS; ++j) {
    float v = acc[j];
#pragma unroll
    for (int off = 32; off > 0; off >>= 1) v += __shfl_down(v, off, 64);
    acc[j] = v;
  }
  __shared__ float part[4][NCLS];
  const int wave = tid >> 6;
  const int lane = tid & 63;
  if (lane == 0) {
#pragma unroll
    for (int j = 0; j < NCLS; ++j) part[wave][j] = acc[j];
  }
  __syncthreads();
  if (tid < NCLS) {
    float s = part[0][tid] + part[1][tid] + part[2][tid] + part[3][tid] + bclf[tid];
    out[(size_t)row * NCLS + tid] = s;
  }
}

extern "C" void kernel_launch(void* const* d_in, const int* in_sizes, int n_in,
                              void* d_out, int out_size, void* d_ws, size_t ws_size,
                              hipStream_t stream) {
  const int* title = (const int*)d_in[0];
  const int* desc  = (const int*)d_in[1];
  const int* t_len = (const int*)d_in[2];
  const int* d_len = (const int*)d_in[3];
  const float* emb   = (const float*)d_in[4];
  const float* W_fc  = (const float*)d_in[5];
  const float* b_fc  = (const float*)d_in[6];
  const float* gamma = (const float*)d_in[7];
  const float* beta  = (const float*)d_in[8];
  const float* W_clf = (const float*)d_in[9];
  const float* b_clf = (const float*)d_in[10];
  float* out = (float*)d_out;

  unsigned char* ws = (unsigned char*)d_ws;
  __hip_bfloat16* swem = (__hip_bfloat16*)ws;                       // 4 MB
  __hip_bfloat16* Wt   = (__hip_bfloat16*)(ws + (4u << 20));        // 4 MB
  float* h     = (float*)(ws + (8u << 20));                         // 4 MB
  float* psum  = (float*)(ws + (12u << 20));                        // 64 KB
  float* psq   = psum + 16 * H_D;
  float* scale = psq + 16 * H_D;
  float* shift = scale + H_D;

  swem_pool_kernel<<<B_SZ, 256, 0, stream>>>(title, desc, t_len, d_len, emb, swem);
  transpose_wfc_kernel<<<dim3(H_D / 64, K_FC / 64), 256, 0, stream>>>(W_fc, Wt);
  gemm_mfma_kernel<<<dim3(H_D / 64, B_SZ / 64), 256, 0, stream>>>(swem, Wt, b_fc, h);
  bn_part_kernel<<<dim3(H_D / 256, 16), 256, 0, stream>>>(h, psum, psq);
  bn_final_kernel<<<H_D / 256, 256, 0, stream>>>(psum, psq, gamma, beta, scale, shift);
  clf_kernel<<<B_SZ, 256, 0, stream>>>(h, scale, shift, W_clf, b_clf, out);
}

// Round 3
// 86.257 us; speedup vs baseline: 2.4023x; 1.4431x over previous
//
#include <hip/hip_runtime.h>
#include <hip/hip_bf16.h>

#define EMB_DIM 512
#define B_SZ 1024
#define LT 50
#define LD 200
#define H_D 1024
#define K_FC 2048   // 4*EMB_DIM
#define NCLS 10
#define BN_EPS 1e-5f
#define NEGV -1e30f

typedef short short8 __attribute__((ext_vector_type(8)));
typedef float f32x4 __attribute__((ext_vector_type(4)));

// XOR swizzle: spread 128B-stride rows across banks (guide §6 G4)
#define SWZ(r, b) ((b) ^ (((r) & 7) << 4))

// ---------------- Kernel 1: SWEM pooling (gather + masked avg/max) --------
// Grid (B, 2): each block owns a 256-dim half-row. 4 waves each own a
// token-residue class (j % 4 == wave); lanes own 4 dims (float4, 16B).
// LDS combine of the 4 wave-partials, then wave 0 writes bf16x4.
__global__ __launch_bounds__(256) void swem_pool_kernel(
    const int* __restrict__ title, const int* __restrict__ desc,
    const int* __restrict__ t_len, const int* __restrict__ d_len,
    const float* __restrict__ emb, __hip_bfloat16* __restrict__ swem) {
  const int b = blockIdx.x;
  const int half = blockIdx.y;
  const int tid = threadIdx.x;
  const int wave = tid >> 6;
  const int lane = tid & 63;
  const int dbase = half * 256 + lane * 4;

  __shared__ float ls_ts[4][256];
  __shared__ float ls_tm[4][256];
  __shared__ float ls_ds[4][256];
  __shared__ float ls_dm[4][256];

  const int tl = t_len[b];
  const int dl = d_len[b];

  // ---- title ----
  float4 s0 = make_float4(0.f, 0.f, 0.f, 0.f), s1 = s0;
  float4 m0 = make_float4(NEGV, NEGV, NEGV, NEGV), m1 = m0;
  {
    int j = wave;
    for (; j + 4 < tl; j += 8) {
      int tok0 = title[b * LT + j];
      int tok1 = title[b * LT + j + 4];
      float4 e0 = *reinterpret_cast<const float4*>(emb + (size_t)tok0 * EMB_DIM + dbase);
      float4 e1 = *reinterpret_cast<const float4*>(emb + (size_t)tok1 * EMB_DIM + dbase);
      s0.x += e0.x; s0.y += e0.y; s0.z += e0.z; s0.w += e0.w;
      m0.x = fmaxf(m0.x, e0.x); m0.y = fmaxf(m0.y, e0.y);
      m0.z = fmaxf(m0.z, e0.z); m0.w = fmaxf(m0.w, e0.w);
      s1.x += e1.x; s1.y += e1.y; s1.z += e1.z; s1.w += e1.w;
      m1.x = fmaxf(m1.x, e1.x); m1.y = fmaxf(m1.y, e1.y);
      m1.z = fmaxf(m1.z, e1.z); m1.w = fmaxf(m1.w, e1.w);
    }
    if (j < tl) {
      int tok0 = title[b * LT + j];
      float4 e0 = *reinterpret_cast<const float4*>(emb + (size_t)tok0 * EMB_DIM + dbase);
      s0.x += e0.x; s0.y += e0.y; s0.z += e0.z; s0.w += e0.w;
      m0.x = fmaxf(m0.x, e0.x); m0.y = fmaxf(m0.y, e0.y);
      m0.z = fmaxf(m0.z, e0.z); m0.w = fmaxf(m0.w, e0.w);
    }
    s0.x += s1.x; s0.y += s1.y; s0.z += s1.z; s0.w += s1.w;
    m0.x = fmaxf(m0.x, m1.x); m0.y = fmaxf(m0.y, m1.y);
    m0.z = fmaxf(m0.z, m1.z); m0.w = fmaxf(m0.w, m1.w);
    *reinterpret_cast<float4*>(&ls_ts[wave][lane * 4]) = s0;
    *reinterpret_cast<float4*>(&ls_tm[wave][lane * 4]) = m0;
  }

  // ---- desc ----
  s0 = make_float4(0.f, 0.f, 0.f, 0.f); s1 = s0;
  m0 = make_float4(NEGV, NEGV, NEGV, NEGV); m1 = m0;
  {
    int j = wave;
    for (; j + 4 < dl; j += 8) {
      int tok0 = desc[b * LD + j];
      int tok1 = desc[b * LD + j + 4];
      float4 e0 = *reinterpret_cast<const float4*>(emb + (size_t)tok0 * EMB_DIM + dbase);
      float4 e1 = *reinterpret_cast<const float4*>(emb + (size_t)tok1 * EMB_DIM + dbase);
      s0.x += e0.x; s0.y += e0.y; s0.z += e0.z; s0.w += e0.w;
      m0.x = fmaxf(m0.x, e0.x); m0.y = fmaxf(m0.y, e0.y);
      m0.z = fmaxf(m0.z, e0.z); m0.w = fmaxf(m0.w, e0.w);
      s1.x += e1.x; s1.y += e1.y; s1.z += e1.z; s1.w += e1.w;
      m1.x = fmaxf(m1.x, e1.x); m1.y = fmaxf(m1.y, e1.y);
      m1.z = fmaxf(m1.z, e1.z); m1.w = fmaxf(m1.w, e1.w);
    }
    if (j < dl) {
      int tok0 = desc[b * LD + j];
      float4 e0 = *reinterpret_cast<const float4*>(emb + (size_t)tok0 * EMB_DIM + dbase);
      s0.x += e0.x; s0.y += e0.y; s0.z += e0.z; s0.w += e0.w;
      m0.x = fmaxf(m0.x, e0.x); m0.y = fmaxf(m0.y, e0.y);
      m0.z = fmaxf(m0.z, e0.z); m0.w = fmaxf(m0.w, e0.w);
    }
    s0.x += s1.x; s0.y += s1.y; s0.z += s1.z; s0.w += s1.w;
    m0.x = fmaxf(m0.x, m1.x); m0.y = fmaxf(m0.y, m1.y);
    m0.z = fmaxf(m0.z, m1.z); m0.w = fmaxf(m0.w, m1.w);
    *reinterpret_cast<float4*>(&ls_ds[wave][lane * 4]) = s0;
    *reinterpret_cast<float4*>(&ls_dm[wave][lane * 4]) = m0;
  }

  __syncthreads();

  if (tid < 64) {
    const float it = 1.0f / (float)tl;
    const float id = 1.0f / (float)dl;
    float4 ts = make_float4(0.f, 0.f, 0.f, 0.f);
    float4 tm = make_float4(NEGV, NEGV, NEGV, NEGV);
    float4 ds = make_float4(0.f, 0.f, 0.f, 0.f);
    float4 dm = make_float4(NEGV, NEGV, NEGV, NEGV);
#pragma unroll
    for (int w = 0; w < 4; ++w) {
      float4 a = *reinterpret_cast<const float4*>(&ls_ts[w][tid * 4]);
      ts.x += a.x; ts.y += a.y; ts.z += a.z; ts.w += a.w;
      float4 bmx = *reinterpret_cast<const float4*>(&ls_tm[w][tid * 4]);
      tm.x = fmaxf(tm.x, bmx.x); tm.y = fmaxf(tm.y, bmx.y);
      tm.z = fmaxf(tm.z, bmx.z); tm.w = fmaxf(tm.w, bmx.w);
      float4 c = *reinterpret_cast<const float4*>(&ls_ds[w][tid * 4]);
      ds.x += c.x; ds.y += c.y; ds.z += c.z; ds.w += c.w;
      float4 dmx = *reinterpret_cast<const float4*>(&ls_dm[w][tid * 4]);
      dm.x = fmaxf(dm.x, dmx.x); dm.y = fmaxf(dm.y, dmx.y);
      dm.z = fmaxf(dm.z, dmx.z); dm.w = fmaxf(dm.w, dmx.w);
    }
    __hip_bfloat16* row = swem + (size_t)b * K_FC + half * 256 + tid * 4;
    union { ushort4 v; __hip_bfloat16 h[4]; } u;
    u.h[0] = __float2bfloat16(ts.x * it); u.h[1] = __float2bfloat16(ts.y * it);
    u.h[2] = __float2bfloat16(ts.z * it); u.h[3] = __float2bfloat16(ts.w * it);
    *reinterpret_cast<ushort4*>(&row[0 * EMB_DIM]) = u.v;
    u.h[0] = __float2bfloat16(tm.x); u.h[1] = __float2bfloat16(tm.y);
    u.h[2] = __float2bfloat16(tm.z); u.h[3] = __float2bfloat16(tm.w);
    *reinterpret_cast<ushort4*>(&row[1 * EMB_DIM]) = u.v;
    u.h[0] = __float2bfloat16(ds.x * id); u.h[1] = __float2bfloat16(ds.y * id);
    u.h[2] = __float2bfloat16(ds.z * id); u.h[3] = __float2bfloat16(ds.w * id);
    *reinterpret_cast<ushort4*>(&row[2 * EMB_DIM]) = u.v;
    u.h[0] = __float2bfloat16(dm.x); u.h[1] = __float2bfloat16(dm.y);
    u.h[2] = __float2bfloat16(dm.z); u.h[3] = __float2bfloat16(dm.w);
    *reinterpret_cast<ushort4*>(&row[3 * EMB_DIM]) = u.v;
  }
}

// ------------- Kernel 2: transpose+convert W_fc [2048][1024]f32 -> Wt [1024][2048]bf16
__global__ __launch_bounds__(256) void transpose_wfc_kernel(
    const float* __restrict__ W, __hip_bfloat16* __restrict__ Wt) {
  __shared__ float t[64][65];
  const int tid = threadIdx.x;
  const int k0 = blockIdx.y * 64;
  const int n0 = blockIdx.x * 64;
#pragma unroll
  for (int i = 0; i < 16; ++i) {
    int idx = i * 256 + tid;
    int r = idx >> 6, c = idx & 63;
    t[r][c] = W[(size_t)(k0 + r) * H_D + n0 + c];
  }
  __syncthreads();
#pragma unroll
  for (int i = 0; i < 16; ++i) {
    int idx = i * 256 + tid;
    int r = idx >> 6, c = idx & 63;
    Wt[(size_t)(n0 + r) * K_FC + k0 + c] = __float2bfloat16(t[c][r]);
  }
}

// ---------------- Kernel 3: MFMA GEMM  h = swem @ W_fc + b_fc (NT, bf16 in, f32 out)
// 64x64 tile, BK=64, 4 waves, each wave 32x32 (2x2 frags of 16x16x32).
__global__ __launch_bounds__(256) void gemm_mfma_kernel(
    const __hip_bfloat16* __restrict__ A,   // [1024][2048] bf16 (swem)
    const __hip_bfloat16* __restrict__ Bt,  // [1024][2048] bf16 (W_fc^T)
    const float* __restrict__ bias, float* __restrict__ C) {
  __shared__ unsigned char As[8192];
  __shared__ unsigned char Bs[8192];
  const int tid = threadIdx.x;
  const int lane = tid & 63;
  const int wave = tid >> 6;
  const int wr = wave >> 1, wc = wave & 1;
  const int m0 = blockIdx.y * 64, n0 = blockIdx.x * 64;

  f32x4 acc[2][2] = {};

  const int c0 = tid * 2, c1 = tid * 2 + 1;
  const int r0s = c0 >> 3, o0 = c0 & 7;
  const int r1s = c1 >> 3, o1 = c1 & 7;
  const int hi = lane >> 4;
  const int lo = lane & 15;

  for (int k0 = 0; k0 < K_FC; k0 += 64) {
    float4 a0 = *reinterpret_cast<const float4*>(A + (size_t)(m0 + r0s) * K_FC + k0 + o0 * 8);
    float4 a1 = *reinterpret_cast<const float4*>(A + (size_t)(m0 + r1s) * K_FC + k0 + o1 * 8);
    float4 b0 = *reinterpret_cast<const float4*>(Bt + (size_t)(n0 + r0s) * K_FC + k0 + o0 * 8);
    float4 b1 = *reinterpret_cast<const float4*>(Bt + (size_t)(n0 + r1s) * K_FC + k0 + o1 * 8);
    __syncthreads();
    *reinterpret_cast<float4*>(As + SWZ(r0s, r0s * 128 + o0 * 16)) = a0;
    *reinterpret_cast<float4*>(As + SWZ(r1s, r1s * 128 + o1 * 16)) = a1;
    *reinterpret_cast<float4*>(Bs + SWZ(r0s, r0s * 128 + o0 * 16)) = b0;
    *reinterpret_cast<float4*>(Bs + SWZ(r1s, r1s * 128 + o1 * 16)) = b1;
    __syncthreads();

#pragma unroll
    for (int kks = 0; kks < 2; ++kks) {
      short8 af[2], bfr[2];
#pragma unroll
      for (int mi = 0; mi < 2; ++mi) {
        int r = wr * 32 + mi * 16 + lo;
        af[mi] = *reinterpret_cast<const short8*>(As + SWZ(r, r * 128 + kks * 64 + hi * 16));
      }
#pragma unroll
      for (int ni = 0; ni < 2; ++ni) {
        int r = wc * 32 + ni * 16 + lo;
        bfr[ni] = *reinterpret_cast<const short8*>(Bs + SWZ(r, r * 128 + kks * 64 + hi * 16));
      }
#pragma unroll
      for (int mi = 0; mi < 2; ++mi)
#pragma unroll
        for (int ni = 0; ni < 2; ++ni)
          acc[mi][ni] = __builtin_amdgcn_mfma_f32_16x16x32_bf16(af[mi], bfr[ni], acc[mi][ni], 0, 0, 0);
    }
  }

#pragma unroll
  for (int mi = 0; mi < 2; ++mi) {
#pragma unroll
    for (int ni = 0; ni < 2; ++ni) {
      int col = n0 + wc * 32 + ni * 16 + lo;
      float bv = bias[col];
#pragma unroll
      for (int r = 0; r < 4; ++r) {
        int rowm = m0 + wr * 32 + mi * 16 + hi * 4 + r;
        C[(size_t)rowm * H_D + col] = acc[mi][ni][r] + bv;
      }
    }
  }
}

// ------------- Kernel 4a: BN partial sums -------------------------------
__global__ __launch_bounds__(256) void bn_part_kernel(
    const float* __restrict__ h, float* __restrict__ psum, float* __restrict__ psq) {
  const int col = blockIdx.x * 256 + threadIdx.x;
  const int r0 = blockIdx.y * 64;
  float s = 0.f, q = 0.f;
  for (int r = r0; r < r0 + 64; ++r) {
    float v = h[(size_t)r * H_D + col];
    s += v;
    q += v * v;
  }
  psum[blockIdx.y * H_D + col] = s;
  psq[blockIdx.y * H_D + col] = q;
}

// ------------- Kernel 4b: finalize BN -> scale/shift ----------------------
__global__ __launch_bounds__(256) void bn_final_kernel(
    const float* __restrict__ psum, const float* __restrict__ psq,
    const float* __restrict__ gamma, const float* __restrict__ beta,
    float* __restrict__ scale, float* __restrict__ shift) {
  const int col = blockIdx.x * 256 + threadIdx.x;
  float s = 0.f, q = 0.f;
#pragma unroll
  for (int i = 0; i < 16; ++i) {
    s += psum[i * H_D + col];
    q += psq[i * H_D + col];
  }
  const float inv_n = 1.0f / (float)B_SZ;
  float mean = s * inv_n;
  float var = q * inv_n - mean * mean;
  float rstd = rsqrtf(var + BN_EPS);
  float sc = rstd * gamma[col];
  scale[col] = sc;
  shift[col] = beta[col] - mean * sc;
}

// ------------- Kernel 5: BN apply + ReLU + classifier GEMM ----------------
__global__ __launch_bounds__(256) void clf_kernel(
    const float* __restrict__ h, const float* __restrict__ scale,
    const float* __restrict__ shift, const float* __restrict__ W,
    const float* __restrict__ bclf, float* __restrict__ out) {
  const int row = blockIdx.x;
  const int tid = threadIdx.x;
  float acc[NCLS] = {};
  for (int k = tid; k < H_D; k += 256) {
    float v = h[(size_t)row * H_D + k] * scale[k] + shift[k];
    v = fmaxf(v, 0.f);
    const float* w = &W[(size_t)k * NCLS];
#pragma unroll
    for (int j = 0; j < NCLS; ++j) acc[j] += v * w[j];
  }
#pragma unroll
  for (int j = 0; j < NCLS; ++j) {
    float v = acc[j];
#pragma unroll
    for (int off = 32; off > 0; off >>= 1) v += __shfl_down(v, off, 64);
    acc[j] = v;
  }
  __shared__ float part[4][NCLS];
  const int wave = tid >> 6;
  const int lane = tid & 63;
  if (lane == 0) {
#pragma unroll
    for (int j = 0; j < NCLS; ++j) part[wave][j] = acc[j];
  }
  __syncthreads();
  if (tid < NCLS) {
    float s = part[0][tid] + part[1][tid] + part[2][tid] + part[3][tid] + bclf[tid];
    out[(size_t)row * NCLS + tid] = s;
  }
}

extern "C" void kernel_launch(void* const* d_in, const int* in_sizes, int n_in,
                              void* d_out, int out_size, void* d_ws, size_t ws_size,
                              hipStream_t stream) {
  const int* title = (const int*)d_in[0];
  const int* desc  = (const int*)d_in[1];
  const int* t_len = (const int*)d_in[2];
  const int* d_len = (const int*)d_in[3];
  const float* emb   = (const float*)d_in[4];
  const float* W_fc  = (const float*)d_in[5];
  const float* b_fc  = (const float*)d_in[6];
  const float* gamma = (const float*)d_in[7];
  const float* beta  = (const float*)d_in[8];
  const float* W_clf = (const float*)d_in[9];
  const float* b_clf = (const float*)d_in[10];
  float* out = (float*)d_out;

  unsigned char* ws = (unsigned char*)d_ws;
  __hip_bfloat16* swem = (__hip_bfloat16*)ws;                       // 4 MB
  __hip_bfloat16* Wt   = (__hip_bfloat16*)(ws + (4u << 20));        // 4 MB
  float* h     = (float*)(ws + (8u << 20));                         // 4 MB
  float* psum  = (float*)(ws + (12u << 20));                        // 64 KB
  float* psq   = psum + 16 * H_D;
  float* scale = psq + 16 * H_D;
  float* shift = scale + H_D;

  swem_pool_kernel<<<dim3(B_SZ, 2), 256, 0, stream>>>(title, desc, t_len, d_len, emb, swem);
  transpose_wfc_kernel<<<dim3(H_D / 64, K_FC / 64), 256, 0, stream>>>(W_fc, Wt);
  gemm_mfma_kernel<<<dim3(H_D / 64, B_SZ / 64), 256, 0, stream>>>(swem, Wt, b_fc, h);
  bn_part_kernel<<<dim3(H_D / 256, 16), 256, 0, stream>>>(h, psum, psq);
  bn_final_kernel<<<H_D / 256, 256, 0, stream>>>(psum, psq, gamma, beta, scale, shift);
  clf_kernel<<<B_SZ, 256, 0, stream>>>(h, scale, shift, W_clf, b_clf, out);
}

// Round 4
// 79.446 us; speedup vs baseline: 2.6083x; 1.0857x over previous
//
#include <hip/hip_runtime.h>
#include <hip/hip_bf16.h>

#define EMB_DIM 512
#define B_SZ 1024
#define LT 50
#define LD 200
#define H_D 1024
#define K_FC 2048   // 4*EMB_DIM
#define NCLS 10
#define BN_EPS 1e-5f
#define NEGV -1e30f

typedef short short8 __attribute__((ext_vector_type(8)));
typedef float f32x4 __attribute__((ext_vector_type(4)));

// XOR swizzle: spread 128B-stride rows across banks (guide §6 G4)
#define SWZ(r, b) ((b) ^ (((r) & 7) << 4))

// ---------------- Kernel 1: fused SWEM pool + W_fc transpose --------------
// Blocks [0, 2*B): pool. Grid-extra blocks: transpose one 64x64 tile of W_fc
// (independent work — hides under the latency-bound pool execution).
// Pool: block owns (batch row b, 256-dim half). 4 waves each own token
// residue class j%4; lanes own 4 dims (float4). Token indices preloaded to
// LDS to break the dependent-load chain. LDS combine, wave 0 writes bf16x4.
__global__ __launch_bounds__(256) void pool_tr_kernel(
    const int* __restrict__ title, const int* __restrict__ desc,
    const int* __restrict__ t_len, const int* __restrict__ d_len,
    const float* __restrict__ emb, __hip_bfloat16* __restrict__ swem,
    const float* __restrict__ W, __hip_bfloat16* __restrict__ Wt) {
  __shared__ float sm[4160];   // pool: 4 groups x 4 waves x 256; tr: 64x65
  __shared__ int idxs[256];    // title 0..49, desc 56..255

  const int bid = blockIdx.x;
  const int tid = threadIdx.x;

  if (bid >= 2 * B_SZ) {
    // ---- W_fc transpose tile: [2048][1024]f32 -> [1024][2048]bf16 ----
    const int t = bid - 2 * B_SZ;
    const int n0 = (t & 15) * 64;
    const int k0 = (t >> 4) * 64;
#pragma unroll
    for (int i = 0; i < 16; ++i) {
      int idx = i * 256 + tid;
      int r = idx >> 6, c = idx & 63;
      sm[r * 65 + c] = W[(size_t)(k0 + r) * H_D + n0 + c];
    }
    __syncthreads();
#pragma unroll
    for (int i = 0; i < 16; ++i) {
      int idx = i * 256 + tid;
      int r = idx >> 6, c = idx & 63;
      Wt[(size_t)(n0 + r) * K_FC + k0 + c] = __float2bfloat16(sm[c * 65 + r]);
    }
    return;
  }

  // ---- pool ----
  const int b = bid >> 1;
  const int half = bid & 1;
  const int wave = tid >> 6;
  const int lane = tid & 63;
  const int dbase = half * 256 + lane * 4;

  if (tid < LT) idxs[tid] = title[b * LT + tid];
  if (tid < LD) idxs[56 + tid] = desc[b * LD + tid];
  const int tl = t_len[b];
  const int dl = d_len[b];
  __syncthreads();

  // title: tokens j == wave (mod 4), unroll 2
  float4 s0 = make_float4(0.f, 0.f, 0.f, 0.f), s1 = s0;
  float4 m0 = make_float4(NEGV, NEGV, NEGV, NEGV), m1 = m0;
  {
    int j = wave;
    for (; j + 4 < tl; j += 8) {
      int tok0 = idxs[j];
      int tok1 = idxs[j + 4];
      float4 e0 = *reinterpret_cast<const float4*>(emb + (size_t)tok0 * EMB_DIM + dbase);
      float4 e1 = *reinterpret_cast<const float4*>(emb + (size_t)tok1 * EMB_DIM + dbase);
      s0.x += e0.x; s0.y += e0.y; s0.z += e0.z; s0.w += e0.w;
      m0.x = fmaxf(m0.x, e0.x); m0.y = fmaxf(m0.y, e0.y);
      m0.z = fmaxf(m0.z, e0.z); m0.w = fmaxf(m0.w, e0.w);
      s1.x += e1.x; s1.y += e1.y; s1.z += e1.z; s1.w += e1.w;
      m1.x = fmaxf(m1.x, e1.x); m1.y = fmaxf(m1.y, e1.y);
      m1.z = fmaxf(m1.z, e1.z); m1.w = fmaxf(m1.w, e1.w);
    }
    if (j < tl) {
      int tok0 = idxs[j];
      float4 e0 = *reinterpret_cast<const float4*>(emb + (size_t)tok0 * EMB_DIM + dbase);
      s0.x += e0.x; s0.y += e0.y; s0.z += e0.z; s0.w += e0.w;
      m0.x = fmaxf(m0.x, e0.x); m0.y = fmaxf(m0.y, e0.y);
      m0.z = fmaxf(m0.z, e0.z); m0.w = fmaxf(m0.w, e0.w);
    }
    s0.x += s1.x; s0.y += s1.y; s0.z += s1.z; s0.w += s1.w;
    m0.x = fmaxf(m0.x, m1.x); m0.y = fmaxf(m0.y, m1.y);
    m0.z = fmaxf(m0.z, m1.z); m0.w = fmaxf(m0.w, m1.w);
    *reinterpret_cast<float4*>(&sm[(0 * 4 + wave) * 256 + lane * 4]) = s0;
    *reinterpret_cast<float4*>(&sm[(1 * 4 + wave) * 256 + lane * 4]) = m0;
  }

  // desc
  s0 = make_float4(0.f, 0.f, 0.f, 0.f); s1 = s0;
  m0 = make_float4(NEGV, NEGV, NEGV, NEGV); m1 = m0;
  {
    int j = wave;
    for (; j + 4 < dl; j += 8) {
      int tok0 = idxs[56 + j];
      int tok1 = idxs[56 + j + 4];
      float4 e0 = *reinterpret_cast<const float4*>(emb + (size_t)tok0 * EMB_DIM + dbase);
      float4 e1 = *reinterpret_cast<const float4*>(emb + (size_t)tok1 * EMB_DIM + dbase);
      s0.x += e0.x; s0.y += e0.y; s0.z += e0.z; s0.w += e0.w;
      m0.x = fmaxf(m0.x, e0.x); m0.y = fmaxf(m0.y, e0.y);
      m0.z = fmaxf(m0.z, e0.z); m0.w = fmaxf(m0.w, e0.w);
      s1.x += e1.x; s1.y += e1.y; s1.z += e1.z; s1.w += e1.w;
      m1.x = fmaxf(m1.x, e1.x); m1.y = fmaxf(m1.y, e1.y);
      m1.z = fmaxf(m1.z, e1.z); m1.w = fmaxf(m1.w, e1.w);
    }
    if (j < dl) {
      int tok0 = idxs[56 + j];
      float4 e0 = *reinterpret_cast<const float4*>(emb + (size_t)tok0 * EMB_DIM + dbase);
      s0.x += e0.x; s0.y += e0.y; s0.z += e0.z; s0.w += e0.w;
      m0.x = fmaxf(m0.x, e0.x); m0.y = fmaxf(m0.y, e0.y);
      m0.z = fmaxf(m0.z, e0.z); m0.w = fmaxf(m0.w, e0.w);
    }
    s0.x += s1.x; s0.y += s1.y; s0.z += s1.z; s0.w += s1.w;
    m0.x = fmaxf(m0.x, m1.x); m0.y = fmaxf(m0.y, m1.y);
    m0.z = fmaxf(m0.z, m1.z); m0.w = fmaxf(m0.w, m1.w);
    *reinterpret_cast<float4*>(&sm[(2 * 4 + wave) * 256 + lane * 4]) = s0;
    *reinterpret_cast<float4*>(&sm[(3 * 4 + wave) * 256 + lane * 4]) = m0;
  }

  __syncthreads();

  if (tid < 64) {
    const float it = 1.0f / (float)tl;
    const float id = 1.0f / (float)dl;
    float4 ts = make_float4(0.f, 0.f, 0.f, 0.f);
    float4 tm = make_float4(NEGV, NEGV, NEGV, NEGV);
    float4 ds = make_float4(0.f, 0.f, 0.f, 0.f);
    float4 dm = make_float4(NEGV, NEGV, NEGV, NEGV);
#pragma unroll
    for (int w = 0; w < 4; ++w) {
      float4 a = *reinterpret_cast<const float4*>(&sm[(0 * 4 + w) * 256 + tid * 4]);
      ts.x += a.x; ts.y += a.y; ts.z += a.z; ts.w += a.w;
      float4 bmx = *reinterpret_cast<const float4*>(&sm[(1 * 4 + w) * 256 + tid * 4]);
      tm.x = fmaxf(tm.x, bmx.x); tm.y = fmaxf(tm.y, bmx.y);
      tm.z = fmaxf(tm.z, bmx.z); tm.w = fmaxf(tm.w, bmx.w);
      float4 c = *reinterpret_cast<const float4*>(&sm[(2 * 4 + w) * 256 + tid * 4]);
      ds.x += c.x; ds.y += c.y; ds.z += c.z; ds.w += c.w;
      float4 dmx = *reinterpret_cast<const float4*>(&sm[(3 * 4 + w) * 256 + tid * 4]);
      dm.x = fmaxf(dm.x, dmx.x); dm.y = fmaxf(dm.y, dmx.y);
      dm.z = fmaxf(dm.z, dmx.z); dm.w = fmaxf(dm.w, dmx.w);
    }
    __hip_bfloat16* row = swem + (size_t)b * K_FC + half * 256 + tid * 4;
    union { ushort4 v; __hip_bfloat16 h[4]; } u;
    u.h[0] = __float2bfloat16(ts.x * it); u.h[1] = __float2bfloat16(ts.y * it);
    u.h[2] = __float2bfloat16(ts.z * it); u.h[3] = __float2bfloat16(ts.w * it);
    *reinterpret_cast<ushort4*>(&row[0 * EMB_DIM]) = u.v;
    u.h[0] = __float2bfloat16(tm.x); u.h[1] = __float2bfloat16(tm.y);
    u.h[2] = __float2bfloat16(tm.z); u.h[3] = __float2bfloat16(tm.w);
    *reinterpret_cast<ushort4*>(&row[1 * EMB_DIM]) = u.v;
    u.h[0] = __float2bfloat16(ds.x * id); u.h[1] = __float2bfloat16(ds.y * id);
    u.h[2] = __float2bfloat16(ds.z * id); u.h[3] = __float2bfloat16(ds.w * id);
    *reinterpret_cast<ushort4*>(&row[2 * EMB_DIM]) = u.v;
    u.h[0] = __float2bfloat16(dm.x); u.h[1] = __float2bfloat16(dm.y);
    u.h[2] = __float2bfloat16(dm.z); u.h[3] = __float2bfloat16(dm.w);
    *reinterpret_cast<ushort4*>(&row[3 * EMB_DIM]) = u.v;
  }
}

// ---------------- Kernel 2: MFMA GEMM + fused BN partial stats ------------
// h = swem @ W_fc^T' + b_fc; also emits per-(mtile,col) sum/sumsq of h.
// 64x64 tile, BK=64, 4 waves, each wave 32x32 (2x2 frags of 16x16x32).
__global__ __launch_bounds__(256) void gemm_mfma_kernel(
    const __hip_bfloat16* __restrict__ A,   // [1024][2048] bf16 (swem)
    const __hip_bfloat16* __restrict__ Bt,  // [1024][2048] bf16 (W_fc^T)
    const float* __restrict__ bias, float* __restrict__ C,
    float* __restrict__ psum, float* __restrict__ psq) {
  __shared__ unsigned char As[8192];
  __shared__ unsigned char Bs[8192];
  __shared__ float reds[2][2][2][16];  // [wr][wc][ni][lo]
  __shared__ float redq[2][2][2][16];
  const int tid = threadIdx.x;
  const int lane = tid & 63;
  const int wave = tid >> 6;
  const int wr = wave >> 1, wc = wave & 1;
  const int m0 = blockIdx.y * 64, n0 = blockIdx.x * 64;

  f32x4 acc[2][2] = {};

  const int c0 = tid * 2, c1 = tid * 2 + 1;
  const int r0s = c0 >> 3, o0 = c0 & 7;
  const int r1s = c1 >> 3, o1 = c1 & 7;
  const int hi = lane >> 4;
  const int lo = lane & 15;

  for (int k0 = 0; k0 < K_FC; k0 += 64) {
    float4 a0 = *reinterpret_cast<const float4*>(A + (size_t)(m0 + r0s) * K_FC + k0 + o0 * 8);
    float4 a1 = *reinterpret_cast<const float4*>(A + (size_t)(m0 + r1s) * K_FC + k0 + o1 * 8);
    float4 b0 = *reinterpret_cast<const float4*>(Bt + (size_t)(n0 + r0s) * K_FC + k0 + o0 * 8);
    float4 b1 = *reinterpret_cast<const float4*>(Bt + (size_t)(n0 + r1s) * K_FC + k0 + o1 * 8);
    __syncthreads();
    *reinterpret_cast<float4*>(As + SWZ(r0s, r0s * 128 + o0 * 16)) = a0;
    *reinterpret_cast<float4*>(As + SWZ(r1s, r1s * 128 + o1 * 16)) = a1;
    *reinterpret_cast<float4*>(Bs + SWZ(r0s, r0s * 128 + o0 * 16)) = b0;
    *reinterpret_cast<float4*>(Bs + SWZ(r1s, r1s * 128 + o1 * 16)) = b1;
    __syncthreads();

#pragma unroll
    for (int kks = 0; kks < 2; ++kks) {
      short8 af[2], bfr[2];
#pragma unroll
      for (int mi = 0; mi < 2; ++mi) {
        int r = wr * 32 + mi * 16 + lo;
        af[mi] = *reinterpret_cast<const short8*>(As + SWZ(r, r * 128 + kks * 64 + hi * 16));
      }
#pragma unroll
      for (int ni = 0; ni < 2; ++ni) {
        int r = wc * 32 + ni * 16 + lo;
        bfr[ni] = *reinterpret_cast<const short8*>(Bs + SWZ(r, r * 128 + kks * 64 + hi * 16));
      }
#pragma unroll
      for (int mi = 0; mi < 2; ++mi)
#pragma unroll
        for (int ni = 0; ni < 2; ++ni)
          acc[mi][ni] = __builtin_amdgcn_mfma_f32_16x16x32_bf16(af[mi], bfr[ni], acc[mi][ni], 0, 0, 0);
    }
  }

  // epilogue: C write (+bias) and per-column partial sum/sumsq.
  // C/D layout: col=lane&15, row=(lane>>4)*4+reg (m89-verified).
#pragma unroll
  for (int ni = 0; ni < 2; ++ni) {
    int col = n0 + wc * 32 + ni * 16 + lo;
    float bv = bias[col];
    float s = 0.f, q = 0.f;
#pragma unroll
    for (int mi = 0; mi < 2; ++mi) {
#pragma unroll
      for (int r = 0; r < 4; ++r) {
        float v = acc[mi][ni][r] + bv;
        s += v; q += v * v;
        int rowm = m0 + wr * 32 + mi * 16 + hi * 4 + r;
        C[(size_t)rowm * H_D + col] = v;
      }
    }
    // reduce over hi (lane bits 4,5): all 32 rows of this wave's M-range
    s += __shfl_xor(s, 16);
    s += __shfl_xor(s, 32);
    q += __shfl_xor(q, 16);
    q += __shfl_xor(q, 32);
    if (lane < 16) { reds[wr][wc][ni][lo] = s; redq[wr][wc][ni][lo] = q; }
  }
  __syncthreads();
  if (tid < 64) {
    int wc2 = tid >> 5, ni2 = (tid >> 4) & 1, lo2 = tid & 15;
    float s = reds[0][wc2][ni2][lo2] + reds[1][wc2][ni2][lo2];
    float q = redq[0][wc2][ni2][lo2] + redq[1][wc2][ni2][lo2];
    psum[blockIdx.y * H_D + n0 + tid] = s;
    psq[blockIdx.y * H_D + n0 + tid] = q;
  }
}

// ------------- Kernel 3: finalize BN -> scale/shift ----------------------
__global__ __launch_bounds__(256) void bn_final_kernel(
    const float* __restrict__ psum, const float* __restrict__ psq,
    const float* __restrict__ gamma, const float* __restrict__ beta,
    float* __restrict__ scale, float* __restrict__ shift) {
  const int col = blockIdx.x * 256 + threadIdx.x;
  float s = 0.f, q = 0.f;
#pragma unroll
  for (int i = 0; i < 16; ++i) {
    s += psum[i * H_D + col];
    q += psq[i * H_D + col];
  }
  const float inv_n = 1.0f / (float)B_SZ;
  float mean = s * inv_n;
  float var = q * inv_n - mean * mean;
  float rstd = rsqrtf(var + BN_EPS);
  float sc = rstd * gamma[col];
  scale[col] = sc;
  shift[col] = beta[col] - mean * sc;
}

// ------------- Kernel 4: BN apply + ReLU + classifier GEMM ----------------
__global__ __launch_bounds__(256) void clf_kernel(
    const float* __restrict__ h, const float* __restrict__ scale,
    const float* __restrict__ shift, const float* __restrict__ W,
    const float* __restrict__ bclf, float* __restrict__ out) {
  const int row = blockIdx.x;
  const int tid = threadIdx.x;
  float acc[NCLS] = {};
  for (int k = tid; k < H_D; k += 256) {
    float v = h[(size_t)row * H_D + k] * scale[k] + shift[k];
    v = fmaxf(v, 0.f);
    const float* w = &W[(size_t)k * NCLS];
#pragma unroll
    for (int j = 0; j < NCLS; ++j) acc[j] += v * w[j];
  }
#pragma unroll
  for (int j = 0; j < NCLS; ++j) {
    float v = acc[j];
#pragma unroll
    for (int off = 32; off > 0; off >>= 1) v += __shfl_down(v, off, 64);
    acc[j] = v;
  }
  __shared__ float part[4][NCLS];
  const int wave = tid >> 6;
  const int lane = tid & 63;
  if (lane == 0) {
#pragma unroll
    for (int j = 0; j < NCLS; ++j) part[wave][j] = acc[j];
  }
  __syncthreads();
  if (tid < NCLS) {
    float s = part[0][tid] + part[1][tid] + part[2][tid] + part[3][tid] + bclf[tid];
    out[(size_t)row * NCLS + tid] = s;
  }
}

extern "C" void kernel_launch(void* const* d_in, const int* in_sizes, int n_in,
                              void* d_out, int out_size, void* d_ws, size_t ws_size,
                              hipStream_t stream) {
  const int* title = (const int*)d_in[0];
  const int* desc  = (const int*)d_in[1];
  const int* t_len = (const int*)d_in[2];
  const int* d_len = (const int*)d_in[3];
  const float* emb   = (const float*)d_in[4];
  const float* W_fc  = (const float*)d_in[5];
  const float* b_fc  = (const float*)d_in[6];
  const float* gamma = (const float*)d_in[7];
  const float* beta  = (const float*)d_in[8];
  const float* W_clf = (const float*)d_in[9];
  const float* b_clf = (const float*)d_in[10];
  float* out = (float*)d_out;

  unsigned char* ws = (unsigned char*)d_ws;
  __hip_bfloat16* swem = (__hip_bfloat16*)ws;                       // 4 MB
  __hip_bfloat16* Wt   = (__hip_bfloat16*)(ws + (4u << 20));        // 4 MB
  float* h     = (float*)(ws + (8u << 20));                         // 4 MB
  float* psum  = (float*)(ws + (12u << 20));                        // 64 KB
  float* psq   = psum + 16 * H_D;
  float* scale = psq + 16 * H_D;
  float* shift = scale + H_D;

  const int n_tr_blocks = (K_FC / 64) * (H_D / 64);  // 512
  pool_tr_kernel<<<2 * B_SZ + n_tr_blocks, 256, 0, stream>>>(
      title, desc, t_len, d_len, emb, swem, W_fc, Wt);
  gemm_mfma_kernel<<<dim3(H_D / 64, B_SZ / 64), 256, 0, stream>>>(swem, Wt, b_fc, h, psum, psq);
  bn_final_kernel<<<H_D / 256, 256, 0, stream>>>(psum, psq, gamma, beta, scale, shift);
  clf_kernel<<<B_SZ, 256, 0, stream>>>(h, scale, shift, W_clf, b_clf, out);
}

// Round 5
// 77.805 us; speedup vs baseline: 2.6633x; 1.0211x over previous
//
#include <hip/hip_runtime.h>
#include <hip/hip_bf16.h>

#define EMB_DIM 512
#define B_SZ 1024
#define LT 50
#define LD 200
#define H_D 1024
#define K_FC 2048   // 4*EMB_DIM
#define NCLS 10
#define BN_EPS 1e-5f
#define NEGV -1e30f

typedef short short8 __attribute__((ext_vector_type(8)));
typedef float f32x4 __attribute__((ext_vector_type(4)));

// XOR swizzle: spread 128B-stride rows across banks (guide §6 G4)
#define SWZ(r, b) ((b) ^ (((r) & 7) << 4))

#define ACC4(S, M, E) \
  S.x += E.x; S.y += E.y; S.z += E.z; S.w += E.w; \
  M.x = fmaxf(M.x, E.x); M.y = fmaxf(M.y, E.y); \
  M.z = fmaxf(M.z, E.z); M.w = fmaxf(M.w, E.w);

// ---------------- Kernel 1: fused SWEM pool + W_fc transpose --------------
// 512 threads. Blocks [0, 2*B): pool one (row, 256-dim half); 8 waves own
// token residues mod 8; lanes own 4 dims (float4). Explicit dual-stream
// load-ahead pipelining (~4 loads in flight/wave). Extra blocks: one 64x64
// W_fc transpose tile each (hides under pool latency).
__global__ __launch_bounds__(512) void pool_tr_kernel(
    const int* __restrict__ title, const int* __restrict__ desc,
    const int* __restrict__ t_len, const int* __restrict__ d_len,
    const float* __restrict__ emb, __hip_bfloat16* __restrict__ swem,
    const float* __restrict__ W, __hip_bfloat16* __restrict__ Wt) {
  __shared__ float sm[8192];   // pool: 4 arrays x 8 waves x 256; tr: 64x65
  __shared__ int idxs[264];    // title [0,50), desc [64,264)

  const int bid = blockIdx.x;
  const int tid = threadIdx.x;

  if (bid >= 2 * B_SZ) {
    // ---- W_fc transpose tile: [2048][1024]f32 -> [1024][2048]bf16 ----
    const int t = bid - 2 * B_SZ;
    const int n0 = (t & 15) * 64;
    const int k0 = (t >> 4) * 64;
#pragma unroll
    for (int i = 0; i < 8; ++i) {
      int idx = i * 512 + tid;
      int r = idx >> 6, c = idx & 63;
      sm[r * 65 + c] = W[(size_t)(k0 + r) * H_D + n0 + c];
    }
    __syncthreads();
#pragma unroll
    for (int i = 0; i < 8; ++i) {
      int idx = i * 512 + tid;
      int r = idx >> 6, c = idx & 63;
      Wt[(size_t)(n0 + r) * K_FC + k0 + c] = __float2bfloat16(sm[c * 65 + r]);
    }
    return;
  }

  // ---- pool ----
  const int b = bid >> 1;
  const int half = bid & 1;
  const int wave = tid >> 6;   // 0..7
  const int lane = tid & 63;
  const int dbase = half * 256 + lane * 4;

  if (tid < LT) idxs[tid] = title[b * LT + tid];
  else if (tid >= 64 && tid < 64 + LD) idxs[tid] = desc[b * LD + tid - 64];
  const int tl = t_len[b];
  const int dl = d_len[b];
  __syncthreads();

  // Process one token list: tokens at positions wave + 8*i, i in [0, cnt).
  // Dual-stream prefetch: streams handle even/odd i with load-ahead-1.
#define POOL_LIST(LEN, IDXOFF, SARR, MARR)                                         \
  {                                                                                \
    float4 s0 = make_float4(0.f, 0.f, 0.f, 0.f), s1 = s0;                          \
    float4 m0 = make_float4(NEGV, NEGV, NEGV, NEGV), m1 = m0;                      \
    const int cnt = (LEN > wave) ? ((LEN - wave + 7) >> 3) : 0;                    \
    if (cnt >= 2) {                                                                \
      float4 e0 = *reinterpret_cast<const float4*>(                                \
          emb + (size_t)idxs[IDXOFF + wave] * EMB_DIM + dbase);                    \
      float4 e1 = *reinterpret_cast<const float4*>(                                \
          emb + (size_t)idxs[IDXOFF + wave + 8] * EMB_DIM + dbase);                \
      int i = 2;                                                                   \
      for (; i + 1 < cnt; i += 2) {                                                \
        float4 n0 = *reinterpret_cast<const float4*>(                              \
            emb + (size_t)idxs[IDXOFF + wave + i * 8] * EMB_DIM + dbase);          \
        float4 n1 = *reinterpret_cast<const float4*>(                              \
            emb + (size_t)idxs[IDXOFF + wave + (i + 1) * 8] * EMB_DIM + dbase);    \
        ACC4(s0, m0, e0); ACC4(s1, m1, e1);                                        \
        e0 = n0; e1 = n1;                                                          \
      }                                                                            \
      ACC4(s0, m0, e0); ACC4(s1, m1, e1);                                          \
      if (i < cnt) {                                                               \
        float4 t2 = *reinterpret_cast<const float4*>(                              \
            emb + (size_t)idxs[IDXOFF + wave + i * 8] * EMB_DIM + dbase);          \
        ACC4(s0, m0, t2);                                                          \
      }                                                                            \
    } else if (cnt == 1) {                                                         \
      float4 e0 = *reinterpret_cast<const float4*>(                                \
          emb + (size_t)idxs[IDXOFF + wave] * EMB_DIM + dbase);                    \
      ACC4(s0, m0, e0);                                                            \
    }                                                                              \
    s0.x += s1.x; s0.y += s1.y; s0.z += s1.z; s0.w += s1.w;                        \
    m0.x = fmaxf(m0.x, m1.x); m0.y = fmaxf(m0.y, m1.y);                            \
    m0.z = fmaxf(m0.z, m1.z); m0.w = fmaxf(m0.w, m1.w);                            \
    *reinterpret_cast<float4*>(&sm[(SARR * 8 + wave) * 256 + lane * 4]) = s0;      \
    *reinterpret_cast<float4*>(&sm[(MARR * 8 + wave) * 256 + lane * 4]) = m0;      \
  }

  POOL_LIST(tl, 0, 0, 1)    // title -> arrays 0 (sum), 1 (max)
  POOL_LIST(dl, 64, 2, 3)   // desc  -> arrays 2 (sum), 3 (max)

  __syncthreads();

  if (tid < 64) {
    const float it = 1.0f / (float)tl;
    const float id = 1.0f / (float)dl;
    float4 ts = make_float4(0.f, 0.f, 0.f, 0.f);
    float4 tm = make_float4(NEGV, NEGV, NEGV, NEGV);
    float4 ds = make_float4(0.f, 0.f, 0.f, 0.f);
    float4 dm = make_float4(NEGV, NEGV, NEGV, NEGV);
#pragma unroll
    for (int w = 0; w < 8; ++w) {
      float4 a = *reinterpret_cast<const float4*>(&sm[(0 * 8 + w) * 256 + tid * 4]);
      ts.x += a.x; ts.y += a.y; ts.z += a.z; ts.w += a.w;
      float4 bmx = *reinterpret_cast<const float4*>(&sm[(1 * 8 + w) * 256 + tid * 4]);
      tm.x = fmaxf(tm.x, bmx.x); tm.y = fmaxf(tm.y, bmx.y);
      tm.z = fmaxf(tm.z, bmx.z); tm.w = fmaxf(tm.w, bmx.w);
      float4 c = *reinterpret_cast<const float4*>(&sm[(2 * 8 + w) * 256 + tid * 4]);
      ds.x += c.x; ds.y += c.y; ds.z += c.z; ds.w += c.w;
      float4 dmx = *reinterpret_cast<const float4*>(&sm[(3 * 8 + w) * 256 + tid * 4]);
      dm.x = fmaxf(dm.x, dmx.x); dm.y = fmaxf(dm.y, dmx.y);
      dm.z = fmaxf(dm.z, dmx.z); dm.w = fmaxf(dm.w, dmx.w);
    }
    __hip_bfloat16* row = swem + (size_t)b * K_FC + half * 256 + tid * 4;
    union { ushort4 v; __hip_bfloat16 h[4]; } u;
    u.h[0] = __float2bfloat16(ts.x * it); u.h[1] = __float2bfloat16(ts.y * it);
    u.h[2] = __float2bfloat16(ts.z * it); u.h[3] = __float2bfloat16(ts.w * it);
    *reinterpret_cast<ushort4*>(&row[0 * EMB_DIM]) = u.v;
    u.h[0] = __float2bfloat16(tm.x); u.h[1] = __float2bfloat16(tm.y);
    u.h[2] = __float2bfloat16(tm.z); u.h[3] = __float2bfloat16(tm.w);
    *reinterpret_cast<ushort4*>(&row[1 * EMB_DIM]) = u.v;
    u.h[0] = __float2bfloat16(ds.x * id); u.h[1] = __float2bfloat16(ds.y * id);
    u.h[2] = __float2bfloat16(ds.z * id); u.h[3] = __float2bfloat16(ds.w * id);
    *reinterpret_cast<ushort4*>(&row[2 * EMB_DIM]) = u.v;
    u.h[0] = __float2bfloat16(dm.x); u.h[1] = __float2bfloat16(dm.y);
    u.h[2] = __float2bfloat16(dm.z); u.h[3] = __float2bfloat16(dm.w);
    *reinterpret_cast<ushort4*>(&row[3 * EMB_DIM]) = u.v;
  }
}

// ---------------- Kernel 2: MFMA GEMM + fused BN partial stats ------------
// h = swem @ W_fc^T' + b_fc; also emits per-(mtile,col) sum/sumsq of h.
// 64x64 tile, BK=64, 4 waves, each wave 32x32 (2x2 frags of 16x16x32).
__global__ __launch_bounds__(256) void gemm_mfma_kernel(
    const __hip_bfloat16* __restrict__ A,   // [1024][2048] bf16 (swem)
    const __hip_bfloat16* __restrict__ Bt,  // [1024][2048] bf16 (W_fc^T)
    const float* __restrict__ bias, float* __restrict__ C,
    float* __restrict__ psum, float* __restrict__ psq) {
  __shared__ unsigned char As[8192];
  __shared__ unsigned char Bs[8192];
  __shared__ float reds[2][2][2][16];  // [wr][wc][ni][lo]
  __shared__ float redq[2][2][2][16];
  const int tid = threadIdx.x;
  const int lane = tid & 63;
  const int wave = tid >> 6;
  const int wr = wave >> 1, wc = wave & 1;
  const int m0 = blockIdx.y * 64, n0 = blockIdx.x * 64;

  f32x4 acc[2][2] = {};

  const int c0 = tid * 2, c1 = tid * 2 + 1;
  const int r0s = c0 >> 3, o0 = c0 & 7;
  const int r1s = c1 >> 3, o1 = c1 & 7;
  const int hi = lane >> 4;
  const int lo = lane & 15;

  for (int k0 = 0; k0 < K_FC; k0 += 64) {
    float4 a0 = *reinterpret_cast<const float4*>(A + (size_t)(m0 + r0s) * K_FC + k0 + o0 * 8);
    float4 a1 = *reinterpret_cast<const float4*>(A + (size_t)(m0 + r1s) * K_FC + k0 + o1 * 8);
    float4 b0 = *reinterpret_cast<const float4*>(Bt + (size_t)(n0 + r0s) * K_FC + k0 + o0 * 8);
    float4 b1 = *reinterpret_cast<const float4*>(Bt + (size_t)(n0 + r1s) * K_FC + k0 + o1 * 8);
    __syncthreads();
    *reinterpret_cast<float4*>(As + SWZ(r0s, r0s * 128 + o0 * 16)) = a0;
    *reinterpret_cast<float4*>(As + SWZ(r1s, r1s * 128 + o1 * 16)) = a1;
    *reinterpret_cast<float4*>(Bs + SWZ(r0s, r0s * 128 + o0 * 16)) = b0;
    *reinterpret_cast<float4*>(Bs + SWZ(r1s, r1s * 128 + o1 * 16)) = b1;
    __syncthreads();

#pragma unroll
    for (int kks = 0; kks < 2; ++kks) {
      short8 af[2], bfr[2];
#pragma unroll
      for (int mi = 0; mi < 2; ++mi) {
        int r = wr * 32 + mi * 16 + lo;
        af[mi] = *reinterpret_cast<const short8*>(As + SWZ(r, r * 128 + kks * 64 + hi * 16));
      }
#pragma unroll
      for (int ni = 0; ni < 2; ++ni) {
        int r = wc * 32 + ni * 16 + lo;
        bfr[ni] = *reinterpret_cast<const short8*>(Bs + SWZ(r, r * 128 + kks * 64 + hi * 16));
      }
#pragma unroll
      for (int mi = 0; mi < 2; ++mi)
#pragma unroll
        for (int ni = 0; ni < 2; ++ni)
          acc[mi][ni] = __builtin_amdgcn_mfma_f32_16x16x32_bf16(af[mi], bfr[ni], acc[mi][ni], 0, 0, 0);
    }
  }

  // epilogue: C write (+bias) and per-column partial sum/sumsq.
  // C/D layout: col=lane&15, row=(lane>>4)*4+reg (m89-verified).
#pragma unroll
  for (int ni = 0; ni < 2; ++ni) {
    int col = n0 + wc * 32 + ni * 16 + lo;
    float bv = bias[col];
    float s = 0.f, q = 0.f;
#pragma unroll
    for (int mi = 0; mi < 2; ++mi) {
#pragma unroll
      for (int r = 0; r < 4; ++r) {
        float v = acc[mi][ni][r] + bv;
        s += v; q += v * v;
        int rowm = m0 + wr * 32 + mi * 16 + hi * 4 + r;
        C[(size_t)rowm * H_D + col] = v;
      }
    }
    s += __shfl_xor(s, 16);
    s += __shfl_xor(s, 32);
    q += __shfl_xor(q, 16);
    q += __shfl_xor(q, 32);
    if (lane < 16) { reds[wr][wc][ni][lo] = s; redq[wr][wc][ni][lo] = q; }
  }
  __syncthreads();
  if (tid < 64) {
    int wc2 = tid >> 5, ni2 = (tid >> 4) & 1, lo2 = tid & 15;
    float s = reds[0][wc2][ni2][lo2] + reds[1][wc2][ni2][lo2];
    float q = redq[0][wc2][ni2][lo2] + redq[1][wc2][ni2][lo2];
    psum[blockIdx.y * H_D + n0 + tid] = s;
    psq[blockIdx.y * H_D + n0 + tid] = q;
  }
}

// ------------- Kernel 3: finalize BN -> scale/shift ----------------------
__global__ __launch_bounds__(256) void bn_final_kernel(
    const float* __restrict__ psum, const float* __restrict__ psq,
    const float* __restrict__ gamma, const float* __restrict__ beta,
    float* __restrict__ scale, float* __restrict__ shift) {
  const int col = blockIdx.x * 256 + threadIdx.x;
  float s = 0.f, q = 0.f;
#pragma unroll
  for (int i = 0; i < 16; ++i) {
    s += psum[i * H_D + col];
    q += psq[i * H_D + col];
  }
  const float inv_n = 1.0f / (float)B_SZ;
  float mean = s * inv_n;
  float var = q * inv_n - mean * mean;
  float rstd = rsqrtf(var + BN_EPS);
  float sc = rstd * gamma[col];
  scale[col] = sc;
  shift[col] = beta[col] - mean * sc;
}

// ------------- Kernel 4: BN apply + ReLU + classifier GEMM ----------------
__global__ __launch_bounds__(256) void clf_kernel(
    const float* __restrict__ h, const float* __restrict__ scale,
    const float* __restrict__ shift, const float* __restrict__ W,
    const float* __restrict__ bclf, float* __restrict__ out) {
  const int row = blockIdx.x;
  const int tid = threadIdx.x;
  float acc[NCLS] = {};
  for (int k = tid; k < H_D; k += 256) {
    float v = h[(size_t)row * H_D + k] * scale[k] + shift[k];
    v = fmaxf(v, 0.f);
    const float* w = &W[(size_t)k * NCLS];
#pragma unroll
    for (int j = 0; j < NCLS; ++j) acc[j] += v * w[j];
  }
#pragma unroll
  for (int j = 0; j < NCLS; ++j) {
    float v = acc[j];
#pragma unroll
    for (int off = 32; off > 0; off >>= 1) v += __shfl_down(v, off, 64);
    acc[j] = v;
  }
  __shared__ float part[4][NCLS];
  const int wave = tid >> 6;
  const int lane = tid & 63;
  if (lane == 0) {
#pragma unroll
    for (int j = 0; j < NCLS; ++j) part[wave][j] = acc[j];
  }
  __syncthreads();
  if (tid < NCLS) {
    float s = part[0][tid] + part[1][tid] + part[2][tid] + part[3][tid] + bclf[tid];
    out[(size_t)row * NCLS + tid] = s;
  }
}

extern "C" void kernel_launch(void* const* d_in, const int* in_sizes, int n_in,
                              void* d_out, int out_size, void* d_ws, size_t ws_size,
                              hipStream_t stream) {
  const int* title = (const int*)d_in[0];
  const int* desc  = (const int*)d_in[1];
  const int* t_len = (const int*)d_in[2];
  const int* d_len = (const int*)d_in[3];
  const float* emb   = (const float*)d_in[4];
  const float* W_fc  = (const float*)d_in[5];
  const float* b_fc  = (const float*)d_in[6];
  const float* gamma = (const float*)d_in[7];
  const float* beta  = (const float*)d_in[8];
  const float* W_clf = (const float*)d_in[9];
  const float* b_clf = (const float*)d_in[10];
  float* out = (float*)d_out;

  unsigned char* ws = (unsigned char*)d_ws;
  __hip_bfloat16* swem = (__hip_bfloat16*)ws;                       // 4 MB
  __hip_bfloat16* Wt   = (__hip_bfloat16*)(ws + (4u << 20));        // 4 MB
  float* h     = (float*)(ws + (8u << 20));                         // 4 MB
  float* psum  = (float*)(ws + (12u << 20));                        // 64 KB
  float* psq   = psum + 16 * H_D;
  float* scale = psq + 16 * H_D;
  float* shift = scale + H_D;

  const int n_tr_blocks = (K_FC / 64) * (H_D / 64);  // 512
  pool_tr_kernel<<<2 * B_SZ + n_tr_blocks, 512, 0, stream>>>(
      title, desc, t_len, d_len, emb, swem, W_fc, Wt);
  gemm_mfma_kernel<<<dim3(H_D / 64, B_SZ / 64), 256, 0, stream>>>(swem, Wt, b_fc, h, psum, psq);
  bn_final_kernel<<<H_D / 256, 256, 0, stream>>>(psum, psq, gamma, beta, scale, shift);
  clf_kernel<<<B_SZ, 256, 0, stream>>>(h, scale, shift, W_clf, b_clf, out);
}

// Round 6
// 74.286 us; speedup vs baseline: 2.7894x; 1.0474x over previous
//
#include <hip/hip_runtime.h>
#include <hip/hip_bf16.h>

#define EMB_DIM 512
#define B_SZ 1024
#define LT 50
#define LD 200
#define H_D 1024
#define K_FC 2048   // 4*EMB_DIM
#define NCLS 10
#define BN_EPS 1e-5f
#define NEGV -1e30f

typedef short short8 __attribute__((ext_vector_type(8)));
typedef float f32x4 __attribute__((ext_vector_type(4)));

// XOR swizzle: spread 128B-stride rows across banks (guide §6 G4)
#define SWZ(r, b) ((b) ^ (((r) & 7) << 4))

#define ACC4(S, M, E) \
  S.x += E.x; S.y += E.y; S.z += E.z; S.w += E.w; \
  M.x = fmaxf(M.x, E.x); M.y = fmaxf(M.y, E.y); \
  M.z = fmaxf(M.z, E.z); M.w = fmaxf(M.w, E.w);

// ---------------- Kernel 1: fused SWEM pool + transposes ------------------
// 512 threads. Blocks [0, 2*B): pool one (row, 256-dim half); 8 waves own
// token residues mod 8. Blocks [2B, 2B+512): one 64x64 W_fc transpose tile.
// Block 2B+512: W_clf transpose (1024x10 -> 10x1024).
__global__ __launch_bounds__(512) void pool_tr_kernel(
    const int* __restrict__ title, const int* __restrict__ desc,
    const int* __restrict__ t_len, const int* __restrict__ d_len,
    const float* __restrict__ emb, __hip_bfloat16* __restrict__ swem,
    const float* __restrict__ W, __hip_bfloat16* __restrict__ Wt,
    const float* __restrict__ Wclf, float* __restrict__ WclfT) {
  __shared__ float sm[8192];   // pool: 4 arrays x 8 waves x 256; tr: 64x65
  __shared__ int idxs[264];    // title [0,50), desc [64,264)

  const int bid = blockIdx.x;
  const int tid = threadIdx.x;

  if (bid >= 2 * B_SZ) {
    const int t = bid - 2 * B_SZ;
    if (t == 512) {
      // ---- W_clf transpose: [1024][10] f32 -> [10][1024] f32 ----
      for (int idx = tid; idx < NCLS * H_D; idx += 512) {
        int j = idx >> 10, k = idx & 1023;
        WclfT[j * H_D + k] = Wclf[(size_t)k * NCLS + j];
      }
      return;
    }
    // ---- W_fc transpose tile: [2048][1024]f32 -> [1024][2048]bf16 ----
    const int n0 = (t & 15) * 64;
    const int k0 = (t >> 4) * 64;
#pragma unroll
    for (int i = 0; i < 8; ++i) {
      int idx = i * 512 + tid;
      int r = idx >> 6, c = idx & 63;
      sm[r * 65 + c] = W[(size_t)(k0 + r) * H_D + n0 + c];
    }
    __syncthreads();
#pragma unroll
    for (int i = 0; i < 8; ++i) {
      int idx = i * 512 + tid;
      int r = idx >> 6, c = idx & 63;
      Wt[(size_t)(n0 + r) * K_FC + k0 + c] = __float2bfloat16(sm[c * 65 + r]);
    }
    return;
  }

  // ---- pool ----
  const int b = bid >> 1;
  const int half = bid & 1;
  const int wave = tid >> 6;   // 0..7
  const int lane = tid & 63;
  const int dbase = half * 256 + lane * 4;

  if (tid < LT) idxs[tid] = title[b * LT + tid];
  else if (tid >= 64 && tid < 64 + LD) idxs[tid] = desc[b * LD + tid - 64];
  const int tl = t_len[b];
  const int dl = d_len[b];
  __syncthreads();

#define POOL_LIST(LEN, IDXOFF, SARR, MARR)                                         \
  {                                                                                \
    float4 s0 = make_float4(0.f, 0.f, 0.f, 0.f), s1 = s0;                          \
    float4 m0 = make_float4(NEGV, NEGV, NEGV, NEGV), m1 = m0;                      \
    const int cnt = (LEN > wave) ? ((LEN - wave + 7) >> 3) : 0;                    \
    if (cnt >= 2) {                                                                \
      float4 e0 = *reinterpret_cast<const float4*>(                                \
          emb + (size_t)idxs[IDXOFF + wave] * EMB_DIM + dbase);                    \
      float4 e1 = *reinterpret_cast<const float4*>(                                \
          emb + (size_t)idxs[IDXOFF + wave + 8] * EMB_DIM + dbase);                \
      int i = 2;                                                                   \
      for (; i + 1 < cnt; i += 2) {                                                \
        float4 n0 = *reinterpret_cast<const float4*>(                              \
            emb + (size_t)idxs[IDXOFF + wave + i * 8] * EMB_DIM + dbase);          \
        float4 n1 = *reinterpret_cast<const float4*>(                              \
            emb + (size_t)idxs[IDXOFF + wave + (i + 1) * 8] * EMB_DIM + dbase);    \
        ACC4(s0, m0, e0); ACC4(s1, m1, e1);                                        \
        e0 = n0; e1 = n1;                                                          \
      }                                                                            \
      ACC4(s0, m0, e0); ACC4(s1, m1, e1);                                          \
      if (i < cnt) {                                                               \
        float4 t2 = *reinterpret_cast<const float4*>(                              \
            emb + (size_t)idxs[IDXOFF + wave + i * 8] * EMB_DIM + dbase);          \
        ACC4(s0, m0, t2);                                                          \
      }                                                                            \
    } else if (cnt == 1) {                                                         \
      float4 e0 = *reinterpret_cast<const float4*>(                                \
          emb + (size_t)idxs[IDXOFF + wave] * EMB_DIM + dbase);                    \
      ACC4(s0, m0, e0);                                                            \
    }                                                                              \
    s0.x += s1.x; s0.y += s1.y; s0.z += s1.z; s0.w += s1.w;                        \
    m0.x = fmaxf(m0.x, m1.x); m0.y = fmaxf(m0.y, m1.y);                            \
    m0.z = fmaxf(m0.z, m1.z); m0.w = fmaxf(m0.w, m1.w);                            \
    *reinterpret_cast<float4*>(&sm[(SARR * 8 + wave) * 256 + lane * 4]) = s0;      \
    *reinterpret_cast<float4*>(&sm[(MARR * 8 + wave) * 256 + lane * 4]) = m0;      \
  }

  POOL_LIST(tl, 0, 0, 1)
  POOL_LIST(dl, 64, 2, 3)

  __syncthreads();

  if (tid < 64) {
    const float it = 1.0f / (float)tl;
    const float id = 1.0f / (float)dl;
    float4 ts = make_float4(0.f, 0.f, 0.f, 0.f);
    float4 tm = make_float4(NEGV, NEGV, NEGV, NEGV);
    float4 ds = make_float4(0.f, 0.f, 0.f, 0.f);
    float4 dm = make_float4(NEGV, NEGV, NEGV, NEGV);
#pragma unroll
    for (int w = 0; w < 8; ++w) {
      float4 a = *reinterpret_cast<const float4*>(&sm[(0 * 8 + w) * 256 + tid * 4]);
      ts.x += a.x; ts.y += a.y; ts.z += a.z; ts.w += a.w;
      float4 bmx = *reinterpret_cast<const float4*>(&sm[(1 * 8 + w) * 256 + tid * 4]);
      tm.x = fmaxf(tm.x, bmx.x); tm.y = fmaxf(tm.y, bmx.y);
      tm.z = fmaxf(tm.z, bmx.z); tm.w = fmaxf(tm.w, bmx.w);
      float4 c = *reinterpret_cast<const float4*>(&sm[(2 * 8 + w) * 256 + tid * 4]);
      ds.x += c.x; ds.y += c.y; ds.z += c.z; ds.w += c.w;
      float4 dmx = *reinterpret_cast<const float4*>(&sm[(3 * 8 + w) * 256 + tid * 4]);
      dm.x = fmaxf(dm.x, dmx.x); dm.y = fmaxf(dm.y, dmx.y);
      dm.z = fmaxf(dm.z, dmx.z); dm.w = fmaxf(dm.w, dmx.w);
    }
    __hip_bfloat16* row = swem + (size_t)b * K_FC + half * 256 + tid * 4;
    union { ushort4 v; __hip_bfloat16 h[4]; } u;
    u.h[0] = __float2bfloat16(ts.x * it); u.h[1] = __float2bfloat16(ts.y * it);
    u.h[2] = __float2bfloat16(ts.z * it); u.h[3] = __float2bfloat16(ts.w * it);
    *reinterpret_cast<ushort4*>(&row[0 * EMB_DIM]) = u.v;
    u.h[0] = __float2bfloat16(tm.x); u.h[1] = __float2bfloat16(tm.y);
    u.h[2] = __float2bfloat16(tm.z); u.h[3] = __float2bfloat16(tm.w);
    *reinterpret_cast<ushort4*>(&row[1 * EMB_DIM]) = u.v;
    u.h[0] = __float2bfloat16(ds.x * id); u.h[1] = __float2bfloat16(ds.y * id);
    u.h[2] = __float2bfloat16(ds.z * id); u.h[3] = __float2bfloat16(ds.w * id);
    *reinterpret_cast<ushort4*>(&row[2 * EMB_DIM]) = u.v;
    u.h[0] = __float2bfloat16(dm.x); u.h[1] = __float2bfloat16(dm.y);
    u.h[2] = __float2bfloat16(dm.z); u.h[3] = __float2bfloat16(dm.w);
    *reinterpret_cast<ushort4*>(&row[3 * EMB_DIM]) = u.v;
  }
}

// ---------------- Kernel 2: MFMA GEMM + fused BN partial stats ------------
// 2-phase prefetch (T3-minimal): issue loads for tile k+1 BEFORE computing
// tile k, so HBM latency hides under the 16-MFMA cluster.
__global__ __launch_bounds__(256) void gemm_mfma_kernel(
    const __hip_bfloat16* __restrict__ A,   // [1024][2048] bf16 (swem)
    const __hip_bfloat16* __restrict__ Bt,  // [1024][2048] bf16 (W_fc^T)
    const float* __restrict__ bias, float* __restrict__ C,
    float* __restrict__ psum, float* __restrict__ psq) {
  __shared__ unsigned char As[8192];
  __shared__ unsigned char Bs[8192];
  __shared__ float reds[2][2][2][16];  // [wr][wc][ni][lo]
  __shared__ float redq[2][2][2][16];
  const int tid = threadIdx.x;
  const int lane = tid & 63;
  const int wave = tid >> 6;
  const int wr = wave >> 1, wc = wave & 1;
  const int m0 = blockIdx.y * 64, n0 = blockIdx.x * 64;

  f32x4 acc[2][2] = {};

  const int c0 = tid * 2, c1 = tid * 2 + 1;
  const int r0s = c0 >> 3, o0 = c0 & 7;
  const int r1s = c1 >> 3, o1 = c1 & 7;
  const int hi = lane >> 4;
  const int lo = lane & 15;

  const __hip_bfloat16* pa0 = A + (size_t)(m0 + r0s) * K_FC + o0 * 8;
  const __hip_bfloat16* pa1 = A + (size_t)(m0 + r1s) * K_FC + o1 * 8;
  const __hip_bfloat16* pb0 = Bt + (size_t)(n0 + r0s) * K_FC + o0 * 8;
  const __hip_bfloat16* pb1 = Bt + (size_t)(n0 + r1s) * K_FC + o1 * 8;

  // prologue: load tile 0
  float4 a0 = *reinterpret_cast<const float4*>(pa0);
  float4 a1 = *reinterpret_cast<const float4*>(pa1);
  float4 b0 = *reinterpret_cast<const float4*>(pb0);
  float4 b1 = *reinterpret_cast<const float4*>(pb1);

  for (int k0 = 0; k0 < K_FC; k0 += 64) {
    __syncthreads();
    *reinterpret_cast<float4*>(As + SWZ(r0s, r0s * 128 + o0 * 16)) = a0;
    *reinterpret_cast<float4*>(As + SWZ(r1s, r1s * 128 + o1 * 16)) = a1;
    *reinterpret_cast<float4*>(Bs + SWZ(r0s, r0s * 128 + o0 * 16)) = b0;
    *reinterpret_cast<float4*>(Bs + SWZ(r1s, r1s * 128 + o1 * 16)) = b1;
    __syncthreads();

    if (k0 + 64 < K_FC) {
      a0 = *reinterpret_cast<const float4*>(pa0 + k0 + 64);
      a1 = *reinterpret_cast<const float4*>(pa1 + k0 + 64);
      b0 = *reinterpret_cast<const float4*>(pb0 + k0 + 64);
      b1 = *reinterpret_cast<const float4*>(pb1 + k0 + 64);
    }

#pragma unroll
    for (int kks = 0; kks < 2; ++kks) {
      short8 af[2], bfr[2];
#pragma unroll
      for (int mi = 0; mi < 2; ++mi) {
        int r = wr * 32 + mi * 16 + lo;
        af[mi] = *reinterpret_cast<const short8*>(As + SWZ(r, r * 128 + kks * 64 + hi * 16));
      }
#pragma unroll
      for (int ni = 0; ni < 2; ++ni) {
        int r = wc * 32 + ni * 16 + lo;
        bfr[ni] = *reinterpret_cast<const short8*>(Bs + SWZ(r, r * 128 + kks * 64 + hi * 16));
      }
#pragma unroll
      for (int mi = 0; mi < 2; ++mi)
#pragma unroll
        for (int ni = 0; ni < 2; ++ni)
          acc[mi][ni] = __builtin_amdgcn_mfma_f32_16x16x32_bf16(af[mi], bfr[ni], acc[mi][ni], 0, 0, 0);
    }
  }

  // epilogue: C write (+bias) and per-column partial sum/sumsq.
#pragma unroll
  for (int ni = 0; ni < 2; ++ni) {
    int col = n0 + wc * 32 + ni * 16 + lo;
    float bv = bias[col];
    float s = 0.f, q = 0.f;
#pragma unroll
    for (int mi = 0; mi < 2; ++mi) {
#pragma unroll
      for (int r = 0; r < 4; ++r) {
        float v = acc[mi][ni][r] + bv;
        s += v; q += v * v;
        int rowm = m0 + wr * 32 + mi * 16 + hi * 4 + r;
        C[(size_t)rowm * H_D + col] = v;
      }
    }
    s += __shfl_xor(s, 16);
    s += __shfl_xor(s, 32);
    q += __shfl_xor(q, 16);
    q += __shfl_xor(q, 32);
    if (lane < 16) { reds[wr][wc][ni][lo] = s; redq[wr][wc][ni][lo] = q; }
  }
  __syncthreads();
  if (tid < 64) {
    int wc2 = tid >> 5, ni2 = (tid >> 4) & 1, lo2 = tid & 15;
    float s = reds[0][wc2][ni2][lo2] + reds[1][wc2][ni2][lo2];
    float q = redq[0][wc2][ni2][lo2] + redq[1][wc2][ni2][lo2];
    psum[blockIdx.y * H_D + n0 + tid] = s;
    psq[blockIdx.y * H_D + n0 + tid] = q;
  }
}

// ------------- Kernel 3: finalize BN -> scale/shift ----------------------
__global__ __launch_bounds__(256) void bn_final_kernel(
    const float* __restrict__ psum, const float* __restrict__ psq,
    const float* __restrict__ gamma, const float* __restrict__ beta,
    float* __restrict__ scale, float* __restrict__ shift) {
  const int col = blockIdx.x * 256 + threadIdx.x;
  float s = 0.f, q = 0.f;
#pragma unroll
  for (int i = 0; i < 16; ++i) {
    s += psum[i * H_D + col];
    q += psq[i * H_D + col];
  }
  const float inv_n = 1.0f / (float)B_SZ;
  float mean = s * inv_n;
  float var = q * inv_n - mean * mean;
  float rstd = rsqrtf(var + BN_EPS);
  float sc = rstd * gamma[col];
  scale[col] = sc;
  shift[col] = beta[col] - mean * sc;
}

// ------------- Kernel 4: BN apply + ReLU + classifier GEMM ----------------
// Block = row. Stage relu(BN(h)) in LDS; wave-per-class coalesced dot.
__global__ __launch_bounds__(256) void clf_kernel(
    const float* __restrict__ h, const float* __restrict__ scale,
    const float* __restrict__ shift, const float* __restrict__ WT,
    const float* __restrict__ bclf, float* __restrict__ out) {
  __shared__ float v[H_D];
  const int row = blockIdx.x;
  const int tid = threadIdx.x;
#pragma unroll
  for (int i = 0; i < 4; ++i) {
    int k = tid + i * 256;
    float x = h[(size_t)row * H_D + k] * scale[k] + shift[k];
    v[k] = fmaxf(x, 0.f);
  }
  __syncthreads();
  const int wave = tid >> 6, lane = tid & 63;
  for (int j = wave; j < NCLS; j += 4) {
    const float* wrow = WT + j * H_D;
    float acc = 0.f;
#pragma unroll
    for (int i = 0; i < 16; ++i) {
      int k = lane + i * 64;
      acc += v[k] * wrow[k];
    }
#pragma unroll
    for (int off = 32; off > 0; off >>= 1) acc += __shfl_down(acc, off, 64);
    if (lane == 0) out[(size_t)row * NCLS + j] = acc + bclf[j];
  }
}

extern "C" void kernel_launch(void* const* d_in, const int* in_sizes, int n_in,
                              void* d_out, int out_size, void* d_ws, size_t ws_size,
                              hipStream_t stream) {
  const int* title = (const int*)d_in[0];
  const int* desc  = (const int*)d_in[1];
  const int* t_len = (const int*)d_in[2];
  const int* d_len = (const int*)d_in[3];
  const float* emb   = (const float*)d_in[4];
  const float* W_fc  = (const float*)d_in[5];
  const float* b_fc  = (const float*)d_in[6];
  const float* gamma = (const float*)d_in[7];
  const float* beta  = (const float*)d_in[8];
  const float* W_clf = (const float*)d_in[9];
  const float* b_clf = (const float*)d_in[10];
  float* out = (float*)d_out;

  unsigned char* ws = (unsigned char*)d_ws;
  __hip_bfloat16* swem = (__hip_bfloat16*)ws;                       // 4 MB
  __hip_bfloat16* Wt   = (__hip_bfloat16*)(ws + (4u << 20));        // 4 MB
  float* h     = (float*)(ws + (8u << 20));                         // 4 MB
  float* psum  = (float*)(ws + (12u << 20));                        // 64 KB
  float* psq   = psum + 16 * H_D;                                   // 64 KB
  float* scale = psq + 16 * H_D;                                    // 4 KB
  float* shift = scale + H_D;                                       // 4 KB
  float* WclfT = shift + H_D;                                       // 40 KB

  const int n_tr_blocks = (K_FC / 64) * (H_D / 64) + 1;  // 512 W_fc + 1 W_clf
  pool_tr_kernel<<<2 * B_SZ + n_tr_blocks, 512, 0, stream>>>(
      title, desc, t_len, d_len, emb, swem, W_fc, Wt, W_clf, WclfT);
  gemm_mfma_kernel<<<dim3(H_D / 64, B_SZ / 64), 256, 0, stream>>>(swem, Wt, b_fc, h, psum, psq);
  bn_final_kernel<<<H_D / 256, 256, 0, stream>>>(psum, psq, gamma, beta, scale, shift);
  clf_kernel<<<B_SZ, 256, 0, stream>>>(h, scale, shift, WclfT, b_clf, out);
}

// Round 7
// 64.307 us; speedup vs baseline: 3.2223x; 1.1552x over previous
//
#include <hip/hip_runtime.h>
#include <hip/hip_bf16.h>

#define EMB_DIM 512
#define B_SZ 1024
#define LT 50
#define LD 200
#define H_D 1024
#define K_FC 2048   // 4*EMB_DIM
#define NCLS 10
#define BN_EPS 1e-5f
#define NEGV -1e30f

typedef short short8 __attribute__((ext_vector_type(8)));
typedef float f32x4 __attribute__((ext_vector_type(4)));

// XOR swizzle: spread 128B-stride rows across banks (guide §6 G4)
#define SWZ(r, b) ((b) ^ (((r) & 7) << 4))

#define ACC4(S, M, E) \
  S.x += E.x; S.y += E.y; S.z += E.z; S.w += E.w; \
  M.x = fmaxf(M.x, E.x); M.y = fmaxf(M.y, E.y); \
  M.z = fmaxf(M.z, E.z); M.w = fmaxf(M.w, E.w);

// ---------------- Kernel 1: fused SWEM pool + transposes ------------------
// (unchanged from R6)
__global__ __launch_bounds__(512) void pool_tr_kernel(
    const int* __restrict__ title, const int* __restrict__ desc,
    const int* __restrict__ t_len, const int* __restrict__ d_len,
    const float* __restrict__ emb, __hip_bfloat16* __restrict__ swem,
    const float* __restrict__ W, __hip_bfloat16* __restrict__ Wt,
    const float* __restrict__ Wclf, float* __restrict__ WclfT) {
  __shared__ float sm[8192];
  __shared__ int idxs[264];

  const int bid = blockIdx.x;
  const int tid = threadIdx.x;

  if (bid >= 2 * B_SZ) {
    const int t = bid - 2 * B_SZ;
    if (t == 512) {
      for (int idx = tid; idx < NCLS * H_D; idx += 512) {
        int j = idx >> 10, k = idx & 1023;
        WclfT[j * H_D + k] = Wclf[(size_t)k * NCLS + j];
      }
      return;
    }
    const int n0 = (t & 15) * 64;
    const int k0 = (t >> 4) * 64;
#pragma unroll
    for (int i = 0; i < 8; ++i) {
      int idx = i * 512 + tid;
      int r = idx >> 6, c = idx & 63;
      sm[r * 65 + c] = W[(size_t)(k0 + r) * H_D + n0 + c];
    }
    __syncthreads();
#pragma unroll
    for (int i = 0; i < 8; ++i) {
      int idx = i * 512 + tid;
      int r = idx >> 6, c = idx & 63;
      Wt[(size_t)(n0 + r) * K_FC + k0 + c] = __float2bfloat16(sm[c * 65 + r]);
    }
    return;
  }

  const int b = bid >> 1;
  const int half = bid & 1;
  const int wave = tid >> 6;
  const int lane = tid & 63;
  const int dbase = half * 256 + lane * 4;

  if (tid < LT) idxs[tid] = title[b * LT + tid];
  else if (tid >= 64 && tid < 64 + LD) idxs[tid] = desc[b * LD + tid - 64];
  const int tl = t_len[b];
  const int dl = d_len[b];
  __syncthreads();

#define POOL_LIST(LEN, IDXOFF, SARR, MARR)                                         \
  {                                                                                \
    float4 s0 = make_float4(0.f, 0.f, 0.f, 0.f), s1 = s0;                          \
    float4 m0 = make_float4(NEGV, NEGV, NEGV, NEGV), m1 = m0;                      \
    const int cnt = (LEN > wave) ? ((LEN - wave + 7) >> 3) : 0;                    \
    if (cnt >= 2) {                                                                \
      float4 e0 = *reinterpret_cast<const float4*>(                                \
          emb + (size_t)idxs[IDXOFF + wave] * EMB_DIM + dbase);                    \
      float4 e1 = *reinterpret_cast<const float4*>(                                \
          emb + (size_t)idxs[IDXOFF + wave + 8] * EMB_DIM + dbase);                \
      int i = 2;                                                                   \
      for (; i + 1 < cnt; i += 2) {                                                \
        float4 n0 = *reinterpret_cast<const float4*>(                              \
            emb + (size_t)idxs[IDXOFF + wave + i * 8] * EMB_DIM + dbase);          \
        float4 n1 = *reinterpret_cast<const float4*>(                              \
            emb + (size_t)idxs[IDXOFF + wave + (i + 1) * 8] * EMB_DIM + dbase);    \
        ACC4(s0, m0, e0); ACC4(s1, m1, e1);                                        \
        e0 = n0; e1 = n1;                                                          \
      }                                                                            \
      ACC4(s0, m0, e0); ACC4(s1, m1, e1);                                          \
      if (i < cnt) {                                                               \
        float4 t2 = *reinterpret_cast<const float4*>(                              \
            emb + (size_t)idxs[IDXOFF + wave + i * 8] * EMB_DIM + dbase);          \
        ACC4(s0, m0, t2);                                                          \
      }                                                                            \
    } else if (cnt == 1) {                                                         \
      float4 e0 = *reinterpret_cast<const float4*>(                                \
          emb + (size_t)idxs[IDXOFF + wave] * EMB_DIM + dbase);                    \
      ACC4(s0, m0, e0);                                                            \
    }                                                                              \
    s0.x += s1.x; s0.y += s1.y; s0.z += s1.z; s0.w += s1.w;                        \
    m0.x = fmaxf(m0.x, m1.x); m0.y = fmaxf(m0.y, m1.y);                            \
    m0.z = fmaxf(m0.z, m1.z); m0.w = fmaxf(m0.w, m1.w);                            \
    *reinterpret_cast<float4*>(&sm[(SARR * 8 + wave) * 256 + lane * 4]) = s0;      \
    *reinterpret_cast<float4*>(&sm[(MARR * 8 + wave) * 256 + lane * 4]) = m0;      \
  }

  POOL_LIST(tl, 0, 0, 1)
  POOL_LIST(dl, 64, 2, 3)

  __syncthreads();

  if (tid < 64) {
    const float it = 1.0f / (float)tl;
    const float id = 1.0f / (float)dl;
    float4 ts = make_float4(0.f, 0.f, 0.f, 0.f);
    float4 tm = make_float4(NEGV, NEGV, NEGV, NEGV);
    float4 ds = make_float4(0.f, 0.f, 0.f, 0.f);
    float4 dm = make_float4(NEGV, NEGV, NEGV, NEGV);
#pragma unroll
    for (int w = 0; w < 8; ++w) {
      float4 a = *reinterpret_cast<const float4*>(&sm[(0 * 8 + w) * 256 + tid * 4]);
      ts.x += a.x; ts.y += a.y; ts.z += a.z; ts.w += a.w;
      float4 bmx = *reinterpret_cast<const float4*>(&sm[(1 * 8 + w) * 256 + tid * 4]);
      tm.x = fmaxf(tm.x, bmx.x); tm.y = fmaxf(tm.y, bmx.y);
      tm.z = fmaxf(tm.z, bmx.z); tm.w = fmaxf(tm.w, bmx.w);
      float4 c = *reinterpret_cast<const float4*>(&sm[(2 * 8 + w) * 256 + tid * 4]);
      ds.x += c.x; ds.y += c.y; ds.z += c.z; ds.w += c.w;
      float4 dmx = *reinterpret_cast<const float4*>(&sm[(3 * 8 + w) * 256 + tid * 4]);
      dm.x = fmaxf(dm.x, dmx.x); dm.y = fmaxf(dm.y, dmx.y);
      dm.z = fmaxf(dm.z, dmx.z); dm.w = fmaxf(dm.w, dmx.w);
    }
    __hip_bfloat16* row = swem + (size_t)b * K_FC + half * 256 + tid * 4;
    union { ushort4 v; __hip_bfloat16 h[4]; } u;
    u.h[0] = __float2bfloat16(ts.x * it); u.h[1] = __float2bfloat16(ts.y * it);
    u.h[2] = __float2bfloat16(ts.z * it); u.h[3] = __float2bfloat16(ts.w * it);
    *reinterpret_cast<ushort4*>(&row[0 * EMB_DIM]) = u.v;
    u.h[0] = __float2bfloat16(tm.x); u.h[1] = __float2bfloat16(tm.y);
    u.h[2] = __float2bfloat16(tm.z); u.h[3] = __float2bfloat16(tm.w);
    *reinterpret_cast<ushort4*>(&row[1 * EMB_DIM]) = u.v;
    u.h[0] = __float2bfloat16(ds.x * id); u.h[1] = __float2bfloat16(ds.y * id);
    u.h[2] = __float2bfloat16(ds.z * id); u.h[3] = __float2bfloat16(ds.w * id);
    *reinterpret_cast<ushort4*>(&row[2 * EMB_DIM]) = u.v;
    u.h[0] = __float2bfloat16(dm.x); u.h[1] = __float2bfloat16(dm.y);
    u.h[2] = __float2bfloat16(dm.z); u.h[3] = __float2bfloat16(dm.w);
    *reinterpret_cast<ushort4*>(&row[3 * EMB_DIM]) = u.v;
  }
}

// ---------------- Kernel 2: MFMA GEMM v3 ----------------------------------
// 64x64 tile, 256 blocks, 512 threads (8 waves 2x4 -> 2 waves/SIMD),
// double-buffered LDS, one barrier per K-step, prefetch depth 2 in regs.
__global__ __launch_bounds__(512) void gemm_mfma_kernel(
    const __hip_bfloat16* __restrict__ A,   // [1024][2048] bf16 (swem)
    const __hip_bfloat16* __restrict__ Bt,  // [1024][2048] bf16 (W_fc^T)
    const float* __restrict__ bias, float* __restrict__ C,
    float* __restrict__ psum, float* __restrict__ psq) {
  __shared__ unsigned char As[2][8192];
  __shared__ unsigned char Bs[2][8192];
  __shared__ float reds[2][4][16];  // [wr][wc][lo]
  __shared__ float redq[2][4][16];
  const int tid = threadIdx.x;
  const int lane = tid & 63;
  const int wave = tid >> 6;        // 0..7
  const int wr = wave >> 2;         // 0,1  (M)
  const int wc = wave & 3;          // 0..3 (N)
  const int m0 = blockIdx.y * 64, n0 = blockIdx.x * 64;

  f32x4 acc[2] = {};                // mi = 0,1

  // staging: 1x16B chunk of A and of B per thread
  const int rs = tid >> 3;          // row 0..63
  const int os = tid & 7;           // 16B slot 0..7
  const int hi = lane >> 4;
  const int lo = lane & 15;

  const __hip_bfloat16* pa = A + (size_t)(m0 + rs) * K_FC + os * 8;
  const __hip_bfloat16* pb = Bt + (size_t)(n0 + rs) * K_FC + os * 8;
  const int swz = SWZ(rs, rs * 128 + os * 16);

  // prologue: tile 0 -> LDS buf 0; tile 1 -> regs
  float4 a1 = *reinterpret_cast<const float4*>(pa);
  float4 b1 = *reinterpret_cast<const float4*>(pb);
  *reinterpret_cast<float4*>(&As[0][swz]) = a1;
  *reinterpret_cast<float4*>(&Bs[0][swz]) = b1;
  a1 = *reinterpret_cast<const float4*>(pa + 64);
  b1 = *reinterpret_cast<const float4*>(pb + 64);
  __syncthreads();

  int cur = 0;
  for (int k0 = 0; k0 < K_FC; k0 += 64) {
    // issue loads for tile k+2 (fly under compute + next barrier)
    float4 an = make_float4(0.f, 0.f, 0.f, 0.f), bn = an;
    if (k0 + 128 < K_FC) {
      an = *reinterpret_cast<const float4*>(pa + k0 + 128);
      bn = *reinterpret_cast<const float4*>(pb + k0 + 128);
    }

    // compute tile k from buf cur
#pragma unroll
    for (int kks = 0; kks < 2; ++kks) {
      short8 af[2];
#pragma unroll
      for (int mi = 0; mi < 2; ++mi) {
        int r = wr * 32 + mi * 16 + lo;
        af[mi] = *reinterpret_cast<const short8*>(&As[cur][SWZ(r, r * 128 + kks * 64 + hi * 16)]);
      }
      int rb = wc * 16 + lo;
      short8 bf = *reinterpret_cast<const short8*>(&Bs[cur][SWZ(rb, rb * 128 + kks * 64 + hi * 16)]);
#pragma unroll
      for (int mi = 0; mi < 2; ++mi)
        acc[mi] = __builtin_amdgcn_mfma_f32_16x16x32_bf16(af[mi], bf, acc[mi], 0, 0, 0);
    }

    // write tile k+1 (regs) to alternate buffer
    if (k0 + 64 < K_FC) {
      *reinterpret_cast<float4*>(&As[cur ^ 1][swz]) = a1;
      *reinterpret_cast<float4*>(&Bs[cur ^ 1][swz]) = b1;
    }
    __syncthreads();
    a1 = an; b1 = bn;
    cur ^= 1;
  }

  // epilogue: C write (+bias) and per-column partial sum/sumsq.
  // C/D layout: col=lane&15, row=(lane>>4)*4+reg (m89-verified).
  {
    int col = n0 + wc * 16 + lo;
    float bv = bias[col];
    float s = 0.f, q = 0.f;
#pragma unroll
    for (int mi = 0; mi < 2; ++mi) {
#pragma unroll
      for (int r = 0; r < 4; ++r) {
        float v = acc[mi][r] + bv;
        s += v; q += v * v;
        int rowm = m0 + wr * 32 + mi * 16 + hi * 4 + r;
        C[(size_t)rowm * H_D + col] = v;
      }
    }
    s += __shfl_xor(s, 16);
    s += __shfl_xor(s, 32);
    q += __shfl_xor(q, 16);
    q += __shfl_xor(q, 32);
    if (lane < 16) { reds[wr][wc][lo] = s; redq[wr][wc][lo] = q; }
  }
  __syncthreads();
  if (tid < 64) {
    int wc2 = tid >> 4, lo2 = tid & 15;
    float s = reds[0][wc2][lo2] + reds[1][wc2][lo2];
    float q = redq[0][wc2][lo2] + redq[1][wc2][lo2];
    psum[blockIdx.y * H_D + n0 + tid] = s;
    psq[blockIdx.y * H_D + n0 + tid] = q;
  }
}

// ------------- Kernel 3: finalize BN -> scale/shift ----------------------
__global__ __launch_bounds__(256) void bn_final_kernel(
    const float* __restrict__ psum, const float* __restrict__ psq,
    const float* __restrict__ gamma, const float* __restrict__ beta,
    float* __restrict__ scale, float* __restrict__ shift) {
  const int col = blockIdx.x * 256 + threadIdx.x;
  float s = 0.f, q = 0.f;
#pragma unroll
  for (int i = 0; i < 16; ++i) {
    s += psum[i * H_D + col];
    q += psq[i * H_D + col];
  }
  const float inv_n = 1.0f / (float)B_SZ;
  float mean = s * inv_n;
  float var = q * inv_n - mean * mean;
  float rstd = rsqrtf(var + BN_EPS);
  float sc = rstd * gamma[col];
  scale[col] = sc;
  shift[col] = beta[col] - mean * sc;
}

// ------------- Kernel 4: BN apply + ReLU + classifier GEMM ----------------
__global__ __launch_bounds__(256) void clf_kernel(
    const float* __restrict__ h, const float* __restrict__ scale,
    const float* __restrict__ shift, const float* __restrict__ WT,
    const float* __restrict__ bclf, float* __restrict__ out) {
  __shared__ float v[H_D];
  const int row = blockIdx.x;
  const int tid = threadIdx.x;
#pragma unroll
  for (int i = 0; i < 4; ++i) {
    int k = tid + i * 256;
    float x = h[(size_t)row * H_D + k] * scale[k] + shift[k];
    v[k] = fmaxf(x, 0.f);
  }
  __syncthreads();
  const int wave = tid >> 6, lane = tid & 63;
  for (int j = wave; j < NCLS; j += 4) {
    const float* wrow = WT + j * H_D;
    float acc = 0.f;
#pragma unroll
    for (int i = 0; i < 16; ++i) {
      int k = lane + i * 64;
      acc += v[k] * wrow[k];
    }
#pragma unroll
    for (int off = 32; off > 0; off >>= 1) acc += __shfl_down(acc, off, 64);
    if (lane == 0) out[(size_t)row * NCLS + j] = acc + bclf[j];
  }
}

extern "C" void kernel_launch(void* const* d_in, const int* in_sizes, int n_in,
                              void* d_out, int out_size, void* d_ws, size_t ws_size,
                              hipStream_t stream) {
  const int* title = (const int*)d_in[0];
  const int* desc  = (const int*)d_in[1];
  const int* t_len = (const int*)d_in[2];
  const int* d_len = (const int*)d_in[3];
  const float* emb   = (const float*)d_in[4];
  const float* W_fc  = (const float*)d_in[5];
  const float* b_fc  = (const float*)d_in[6];
  const float* gamma = (const float*)d_in[7];
  const float* beta  = (const float*)d_in[8];
  const float* W_clf = (const float*)d_in[9];
  const float* b_clf = (const float*)d_in[10];
  float* out = (float*)d_out;

  unsigned char* ws = (unsigned char*)d_ws;
  __hip_bfloat16* swem = (__hip_bfloat16*)ws;                       // 4 MB
  __hip_bfloat16* Wt   = (__hip_bfloat16*)(ws + (4u << 20));        // 4 MB
  float* h     = (float*)(ws + (8u << 20));                         // 4 MB
  float* psum  = (float*)(ws + (12u << 20));                        // 64 KB
  float* psq   = psum + 16 * H_D;                                   // 64 KB
  float* scale = psq + 16 * H_D;                                    // 4 KB
  float* shift = scale + H_D;                                       // 4 KB
  float* WclfT = shift + H_D;                                       // 40 KB

  const int n_tr_blocks = (K_FC / 64) * (H_D / 64) + 1;  // 512 W_fc + 1 W_clf
  pool_tr_kernel<<<2 * B_SZ + n_tr_blocks, 512, 0, stream>>>(
      title, desc, t_len, d_len, emb, swem, W_fc, Wt, W_clf, WclfT);
  gemm_mfma_kernel<<<dim3(H_D / 64, B_SZ / 64), 512, 0, stream>>>(swem, Wt, b_fc, h, psum, psq);
  bn_final_kernel<<<H_D / 256, 256, 0, stream>>>(psum, psq, gamma, beta, scale, shift);
  clf_kernel<<<B_SZ, 256, 0, stream>>>(h, scale, shift, WclfT, b_clf, out);
}